// Round 3
// baseline (1138.093 us; speedup 1.0000x reference)
//
#include <hip/hip_runtime.h>

#define HDIM 256
#define LNEPS 1e-5f

typedef float f32x4 __attribute__((ext_vector_type(4)));
typedef short bf16x8 __attribute__((ext_vector_type(8)));

static __device__ __forceinline__ unsigned short f2b(float f) {
  union { float f; unsigned u; } v; v.f = f;
  return (unsigned short)((v.u + 0x7fffu + ((v.u >> 16) & 1u)) >> 16);
}
static __device__ __forceinline__ unsigned pk2(float lo, float hi) {
  return (unsigned)f2b(lo) | ((unsigned)f2b(hi) << 16);
}

// ---------------- transpose + bf16 convert: in[K][N] -> out[N][K] ----------------
__global__ void cvtw_kernel(const float* __restrict__ in, unsigned short* __restrict__ out,
                            int K, int N) {
  int idx = blockIdx.x * 256 + threadIdx.x;
  if (idx >= K * N) return;
  int k = idx / N, n = idx - k * N;
  out[(size_t)n * K + k] = f2b(in[idx]);
}

// ---------------- per-graph counts ----------------
__global__ void count_kernel(const int* __restrict__ node_gid, const int* __restrict__ bond_gid,
                             int* cnt_node, int* cnt_bond, int N, int E) {
  int i = blockIdx.x * 256 + threadIdx.x;
  if (i < N) atomicAdd(&cnt_node[node_gid[i]], 1);
  if (i < E) atomicAdd(&cnt_bond[bond_gid[i]], 1);
}

__global__ void factor_kernel(const int* __restrict__ cnt_node, const int* __restrict__ cnt_bond,
                              float* fac_node, float* fac_bond, float* recip_node, int G) {
  int g = blockIdx.x * 256 + threadIdx.x;
  if (g >= G) return;
  float cn = fmaxf((float)cnt_node[g], 1.f);
  float cb = fmaxf((float)cnt_bond[g], 1.f);
  fac_node[g] = rsqrtf(cn);
  fac_bond[g] = rsqrtf(cb);
  recip_node[g] = 1.f / cn;
}

// ---------------- CSR build ----------------
__global__ void deg_kernel(const int* __restrict__ dst, int* __restrict__ deg, int n) {
  int i = blockIdx.x * 256 + threadIdx.x;
  if (i < n) atomicAdd(&deg[dst[i]], 1);
}

__global__ void scan1_kernel(const int* __restrict__ deg, int* __restrict__ excl,
                             int* __restrict__ bsum, int n) {
  int t = threadIdx.x;
  int i = blockIdx.x * 256 + t;
  int v = (i < n) ? deg[i] : 0;
  int lane = t & 63, w = t >> 6;
  int s = v;
#pragma unroll
  for (int d = 1; d < 64; d <<= 1) {
    int u = __shfl_up(s, d);
    if (lane >= d) s += u;
  }
  __shared__ int wsum[4];
  if (lane == 63) wsum[w] = s;
  __syncthreads();
  int base = 0;
  for (int ww = 0; ww < w; ++ww) base += wsum[ww];
  if (i < n) excl[i] = base + s - v;
  if (t == 255) bsum[blockIdx.x] = base + s;
}

__global__ void scan2_kernel(int* __restrict__ bsum, int nb) {
  int t = threadIdx.x;  // 1024 threads
  int v = (t < nb) ? bsum[t] : 0;
  int lane = t & 63, w = t >> 6;
  int s = v;
#pragma unroll
  for (int d = 1; d < 64; d <<= 1) {
    int u = __shfl_up(s, d);
    if (lane >= d) s += u;
  }
  __shared__ int wsum[16];
  if (lane == 63) wsum[w] = s;
  __syncthreads();
  int base = 0;
  for (int ww = 0; ww < w; ++ww) base += wsum[ww];
  if (t < nb) bsum[t] = base + s - v;
}

__global__ void scan3_kernel(int* __restrict__ excl, const int* __restrict__ bsum, int n) {
  int i = blockIdx.x * 256 + threadIdx.x;
  if (i < n) excl[i] += bsum[blockIdx.x];
}

__global__ void fill_kernel(const int* __restrict__ dst, const int* __restrict__ off,
                            int* __restrict__ cursor, int* __restrict__ csr, int n) {
  int i = blockIdx.x * 256 + threadIdx.x;
  if (i >= n) return;
  int d = dst[i];
  int p = atomicAdd(&cursor[d], 1);
  csr[off[d] + p] = i;
}

// ---------------- fused gather + MLP + LayerNorm + graph_normal + residual (+pool) ----
// 32 rows/block, 256 threads (4 waves), LDS 33.3KB -> 4 blocks/CU.
// GATHER IS COLUMN-SPLIT: 256 threads = 32 rows x 8 col-slices; each thread owns 32
// contiguous columns of ONE row. All 32 rows in flight at once; per-edge loads are
// independent 16B vectors -> deep ILP (fix for round-2's serial pointer-chase).
// MODE 0: edge update (RBF in registers, fully unrolled k). MODE 1: node update (+pool).
template <int MODE>
__global__ __launch_bounds__(256, 4) void fused_mlp_kernel(
    const float* __restrict__ hsrc,    // MODE0: edge_hidden ; MODE1: node_hidden
    const float* __restrict__ eextra,  // MODE0: bond_angle[A] ; MODE1: edge_out rows
    const int* __restrict__ srcidx,    // MODE0: ba_src ; MODE1: ab_src
    const int* __restrict__ off, const int* __restrict__ deg, const int* __restrict__ csr,
    const float* __restrict__ rbf_w, const float* __restrict__ rbf_b,
    const float* __restrict__ residual, const int* __restrict__ gid,
    const float* __restrict__ gfactor,
    const unsigned short* __restrict__ w1t, const float* __restrict__ b1,
    const unsigned short* __restrict__ w2t, const float* __restrict__ b2,
    const float* __restrict__ ln_g, const float* __restrict__ ln_b,
    float* __restrict__ out_rows, float* pool_out, int M) {
  __shared__ __align__(16) char smem[33280];
  char* Xb = smem;                        // bf16 [32][256] swizzled, 16KB
  char* Hb = smem + 16384;                // bf16 [32][256] (one half of H1), 16KB
  float* Outs = (float*)smem;             // f32 [32][256], overlays Xb+Hb after GEMMs
  float* fstat = (float*)(smem + 32768);  // [32][2] mean/rstd
  float* gfs = (float*)(smem + 33024);    // [32]
  int* gid_s = (int*)(smem + 33152);      // [32]

  int t = threadIdx.x;
  int row0 = blockIdx.x * 32;
  int w = t >> 6, lane = t & 63;
  int l15 = lane & 15, lg = lane >> 4;

  // ---- fused gather, column-split: thread owns row r, cols c0..c0+31 ----
  {
    int r = t >> 3, sub = t & 7;
    int c0 = sub * 32;
    int d = row0 + r;
    f32x4 acc[8];
#pragma unroll
    for (int i = 0; i < 8; ++i) acc[i] = (f32x4)0.f;

    if (t < 32) {
      int rr = row0 + t;
      int g = (rr < M) ? gid[rr] : 0;
      gid_s[t] = g;
      gfs[t] = gfactor[g];
    }

    if (d < M) {
      int start = off[d], cnt = deg[d];
      if (MODE == 0) {
        float R[32];
#pragma unroll
        for (int k = 0; k < 32; ++k) R[k] = 0.f;
        for (int j = 0; j < cnt; ++j) {
          int a = csr[start + j];
          float av = eextra[a];
          int s = srcidx[a];
          const float* hp = &hsrc[(size_t)s * HDIM + c0];
#pragma unroll
          for (int i = 0; i < 8; ++i) acc[i] += *(const f32x4*)(hp + i * 4);
#pragma unroll
          for (int k = 0; k < 32; ++k) {
            float dd = av - 0.1f * (float)k;
            R[k] += __expf(-10.f * dd * dd);
          }
        }
        // acc += R @ rbf_w col-slice  (rbf_w is 32KB, L1-resident)
#pragma unroll
        for (int k = 0; k < 32; ++k) {
          const float* wp = &rbf_w[k * HDIM + c0];
          f32x4 rv = (f32x4)R[k];
#pragma unroll
          for (int i = 0; i < 8; ++i) acc[i] += rv * (*(const f32x4*)(wp + i * 4));
        }
        float fc = (float)cnt;
        const float* bp = &rbf_b[c0];
#pragma unroll
        for (int i = 0; i < 8; ++i) acc[i] += ((f32x4)fc) * (*(const f32x4*)(bp + i * 4));
      } else {
        for (int j = 0; j < cnt; ++j) {
          int e = csr[start + j];
          int s = srcidx[e];
          const float* ep = &eextra[(size_t)e * HDIM + c0];
          const float* np = &hsrc[(size_t)s * HDIM + c0];
#pragma unroll
          for (int i = 0; i < 8; ++i) {
            acc[i] += *(const f32x4*)(ep + i * 4);
            acc[i] += *(const f32x4*)(np + i * 4);
          }
        }
      }
    }
    // write Xb (swizzled bf16), 4x 16B chunks
#pragma unroll
    for (int i = 0; i < 4; ++i) {
      int cc = c0 + i * 8;
      int byte = (r * 512 + cc * 2) ^ ((r & 7) << 4);
      *(uint4*)(Xb + byte) =
          make_uint4(pk2(acc[2 * i][0], acc[2 * i][1]), pk2(acc[2 * i][2], acc[2 * i][3]),
                     pk2(acc[2 * i + 1][0], acc[2 * i + 1][1]),
                     pk2(acc[2 * i + 1][2], acc[2 * i + 1][3]));
    }
  }
  __syncthreads();

  f32x4 acc2[2][4];  // [mt][nf] : row m = mt*16 + lg*4 + jr ; col n2 = w*64 + nf*16 + l15
#pragma unroll
  for (int mt = 0; mt < 2; ++mt)
#pragma unroll
    for (int nf = 0; nf < 4; ++nf) acc2[mt][nf] = (f32x4)0.f;

  for (int h = 0; h < 2; ++h) {
    // ---- GEMM1 (swapped): D[n1][m]; wave's n1 tiles = h*256 + w*64 + tt*16 ----
    f32x4 acc1[4][2];
#pragma unroll
    for (int tt = 0; tt < 4; ++tt)
#pragma unroll
      for (int mt = 0; mt < 2; ++mt) acc1[tt][mt] = (f32x4)0.f;

    const unsigned short* a1p = w1t + (size_t)(h * 256 + w * 64 + l15) * 256 + lg * 8;
#pragma unroll
    for (int kk = 0; kk < 8; ++kk) {
      bf16x8 xfr[2];
#pragma unroll
      for (int mt = 0; mt < 2; ++mt) {
        int m = mt * 16 + l15;
        int byte = (m * 512 + kk * 64 + lg * 16) ^ ((m & 7) << 4);
        xfr[mt] = *(const bf16x8*)(Xb + byte);
      }
#pragma unroll
      for (int tt = 0; tt < 4; ++tt) {
        bf16x8 afr = *(const bf16x8*)(a1p + tt * 16 * 256 + kk * 32);
#pragma unroll
        for (int mt = 0; mt < 2; ++mt)
          acc1[tt][mt] = __builtin_amdgcn_mfma_f32_16x16x32_bf16(afr, xfr[mt], acc1[tt][mt], 0, 0, 0);
      }
    }

    // ---- bias + relu + packed H1 store: H1[m][n1], n1 = w*64 + tt*16 + lg*4 + r ----
#pragma unroll
    for (int tt = 0; tt < 4; ++tt) {
      f32x4 b1v = *(const f32x4*)&b1[h * 256 + w * 64 + tt * 16 + lg * 4];
#pragma unroll
      for (int mt = 0; mt < 2; ++mt) {
        f32x4 v = acc1[tt][mt] + b1v;
        v[0] = fmaxf(v[0], 0.f); v[1] = fmaxf(v[1], 0.f);
        v[2] = fmaxf(v[2], 0.f); v[3] = fmaxf(v[3], 0.f);
        int m = mt * 16 + l15;
        int n1 = w * 64 + tt * 16 + lg * 4;  // within this half
        int byte = (m * 512 + n1 * 2) ^ ((m & 7) << 4);
        *(uint2*)(Hb + byte) = make_uint2(pk2(v[0], v[1]), pk2(v[2], v[3]));
      }
    }
    __syncthreads();

    // ---- GEMM2 partial: A = H1 rows (LDS), B = w2t cols (L2) ----
    const unsigned short* w2p = w2t + (size_t)(w * 64 + l15) * 512 + h * 256 + lg * 8;
#pragma unroll
    for (int kk = 0; kk < 8; ++kk) {
      bf16x8 hfr[2];
#pragma unroll
      for (int mt = 0; mt < 2; ++mt) {
        int m = mt * 16 + l15;
        int byte = (m * 512 + kk * 64 + lg * 16) ^ ((m & 7) << 4);
        hfr[mt] = *(const bf16x8*)(Hb + byte);
      }
#pragma unroll
      for (int nf = 0; nf < 4; ++nf) {
        bf16x8 wfr = *(const bf16x8*)(w2p + nf * 16 * 512 + kk * 32);
#pragma unroll
        for (int mt = 0; mt < 2; ++mt)
          acc2[mt][nf] = __builtin_amdgcn_mfma_f32_16x16x32_bf16(hfr[mt], wfr, acc2[mt][nf], 0, 0, 0);
      }
    }
    __syncthreads();
  }

  // ---- Outs = acc2 + b2 (f32 LDS) ----
#pragma unroll
  for (int nf = 0; nf < 4; ++nf) {
    float b2v = b2[w * 64 + nf * 16 + l15];
#pragma unroll
    for (int mt = 0; mt < 2; ++mt)
#pragma unroll
      for (int jr = 0; jr < 4; ++jr)
        Outs[(mt * 16 + lg * 4 + jr) * 256 + (w * 64 + nf * 16 + l15)] = acc2[mt][nf][jr] + b2v;
  }
  __syncthreads();

  // ---- LayerNorm stats: 8 threads per row ----
  {
    int row = t >> 3, sub = t & 7;
    float s = 0.f, ss = 0.f;
#pragma unroll
    for (int i = 0; i < 8; ++i) {
      f32x4 v = *(const f32x4*)&Outs[row * 256 + sub * 32 + i * 4];
      s += v[0] + v[1] + v[2] + v[3];
      ss += v[0] * v[0] + v[1] * v[1] + v[2] * v[2] + v[3] * v[3];
    }
    s += __shfl_xor(s, 1); ss += __shfl_xor(ss, 1);
    s += __shfl_xor(s, 2); ss += __shfl_xor(ss, 2);
    s += __shfl_xor(s, 4); ss += __shfl_xor(ss, 4);
    if (sub == 0) {
      float mean = s * (1.f / 256.f);
      float var = ss * (1.f / 256.f) - mean * mean;
      fstat[row * 2] = mean;
      fstat[row * 2 + 1] = rsqrtf(var + LNEPS);
    }
  }
  __syncthreads();

  // ---- finalize: LN affine, graph_normal, residual, store (+segmented pool) ----
  {
    float g_t = ln_g[t], bb_t = ln_b[t];
    float psum = 0.f;
    int curg = -1;
    for (int p = 0; p < 32; ++p) {
      int gr = row0 + p;
      if (gr < M) {
        float v = Outs[p * 256 + t];
        v = (v - fstat[p * 2]) * fstat[p * 2 + 1] * g_t + bb_t;
        v *= gfs[p];
        v += residual[(size_t)gr * HDIM + t];
        out_rows[(size_t)gr * HDIM + t] = v;
        if (MODE == 1) {
          int g = gid_s[p];
          if (g != curg) {
            if (curg >= 0) atomicAdd(&pool_out[(size_t)curg * HDIM + t], psum);
            psum = 0.f;
            curg = g;
          }
          psum += v;
        }
      }
    }
    if (MODE == 1 && curg >= 0) atomicAdd(&pool_out[(size_t)curg * HDIM + t], psum);
  }
}

// ---------------- pooled sums -> means ----------------
__global__ void pooldiv_kernel(float* out_graph, const float* __restrict__ recip_node) {
  int g = blockIdx.x, t = threadIdx.x;
  out_graph[(size_t)g * HDIM + t] *= recip_node[g];
}

extern "C" void kernel_launch(void* const* d_in, const int* in_sizes, int n_in,
                              void* d_out, int out_size, void* d_ws, size_t ws_size,
                              hipStream_t stream) {
  const float* node_hidden = (const float*)d_in[0];
  const float* edge_hidden = (const float*)d_in[1];
  const float* bond_angle = (const float*)d_in[2];
  const int* ab_src = (const int*)d_in[3];
  const int* ab_dst = (const int*)d_in[4];
  const int* ba_src = (const int*)d_in[5];
  const int* ba_dst = (const int*)d_in[6];
  const int* node_gid = (const int*)d_in[7];
  const int* bond_gid = (const int*)d_in[8];
  const float* rbf_w = (const float*)d_in[10];
  const float* rbf_b = (const float*)d_in[11];
  const float* ba_w1 = (const float*)d_in[12];
  const float* ba_b1 = (const float*)d_in[13];
  const float* ba_w2 = (const float*)d_in[14];
  const float* ba_b2 = (const float*)d_in[15];
  const float* ba_ln_g = (const float*)d_in[16];
  const float* ba_ln_b = (const float*)d_in[17];
  const float* ab_w1 = (const float*)d_in[18];
  const float* ab_b1 = (const float*)d_in[19];
  const float* ab_w2 = (const float*)d_in[20];
  const float* ab_b2 = (const float*)d_in[21];
  const float* ab_ln_g = (const float*)d_in[22];
  const float* ab_ln_b = (const float*)d_in[23];

  int N = in_sizes[0] / HDIM;
  int E = in_sizes[1] / HDIM;
  int A = in_sizes[2];
  int G = out_size / HDIM - N - E;

  float* out_node = (float*)d_out;
  float* out_edge = out_node + (size_t)N * HDIM;
  float* out_graph = out_edge + (size_t)E * HDIM;

  // ---- workspace layout ----
  char* ws = (char*)d_ws;
  int* cnt_node = (int*)ws;                    // G   (zeroed)
  int* cnt_bond = cnt_node + G;                // G   (zeroed)
  int* deg_e = cnt_bond + G;                   // E   (zeroed)
  int* cur_e = deg_e + E;                      // E   (zeroed)
  int* deg_n = cur_e + E;                      // N   (zeroed)
  int* cur_n = deg_n + N;                      // N   (zeroed)
  size_t zero_bytes = (size_t)(2 * G + 2 * E + 2 * N) * 4;
  float* fac_node = (float*)(cur_n + N);       // G
  float* fac_bond = fac_node + G;              // G
  float* recip_node = fac_bond + G;            // G
  int* off_e = (int*)(recip_node + G);         // E
  int* csr_e = off_e + E;                      // A
  int* off_n = csr_e + A;                      // N
  int* csr_n = off_n + N;                      // E
  int* bsum = csr_n + E;                       // 1024
  size_t off = ((size_t)((char*)(bsum + 1024) - ws) + 255) & ~(size_t)255;
  unsigned short* w1t_ba = (unsigned short*)(ws + off); off += (size_t)512 * 256 * 2;
  unsigned short* w2t_ba = (unsigned short*)(ws + off); off += (size_t)256 * 512 * 2;
  unsigned short* w1t_ab = (unsigned short*)(ws + off); off += (size_t)512 * 256 * 2;
  unsigned short* w2t_ab = (unsigned short*)(ws + off); off += (size_t)256 * 512 * 2;

  hipMemsetAsync(d_ws, 0, zero_bytes, stream);
  hipMemsetAsync(out_graph, 0, (size_t)G * HDIM * 4, stream);

  int wgrid = (256 * 512 + 255) / 256;
  cvtw_kernel<<<wgrid, 256, 0, stream>>>(ba_w1, w1t_ba, 256, 512);
  cvtw_kernel<<<wgrid, 256, 0, stream>>>(ba_w2, w2t_ba, 512, 256);
  cvtw_kernel<<<wgrid, 256, 0, stream>>>(ab_w1, w1t_ab, 256, 512);
  cvtw_kernel<<<wgrid, 256, 0, stream>>>(ab_w2, w2t_ab, 512, 256);

  count_kernel<<<(E + 255) / 256, 256, 0, stream>>>(node_gid, bond_gid, cnt_node, cnt_bond, N, E);
  factor_kernel<<<(G + 255) / 256, 256, 0, stream>>>(cnt_node, cnt_bond, fac_node, fac_bond,
                                                     recip_node, G);

  // ---- CSR for bond-angle graph ----
  deg_kernel<<<(A + 255) / 256, 256, 0, stream>>>(ba_dst, deg_e, A);
  int nbE = (E + 255) / 256;
  scan1_kernel<<<nbE, 256, 0, stream>>>(deg_e, off_e, bsum, E);
  scan2_kernel<<<1, 1024, 0, stream>>>(bsum, nbE);
  scan3_kernel<<<nbE, 256, 0, stream>>>(off_e, bsum, E);
  fill_kernel<<<(A + 255) / 256, 256, 0, stream>>>(ba_dst, off_e, cur_e, csr_e, A);

  // ---- fused gather + MLP for bond features ----
  fused_mlp_kernel<0><<<(E + 31) / 32, 256, 0, stream>>>(
      edge_hidden, bond_angle, ba_src, off_e, deg_e, csr_e, rbf_w, rbf_b,
      edge_hidden, bond_gid, fac_bond, w1t_ba, ba_b1, w2t_ba, ba_b2,
      ba_ln_g, ba_ln_b, out_edge, nullptr, E);

  // ---- CSR for atom-bond graph ----
  deg_kernel<<<(E + 255) / 256, 256, 0, stream>>>(ab_dst, deg_n, E);
  int nbN = (N + 255) / 256;
  scan1_kernel<<<nbN, 256, 0, stream>>>(deg_n, off_n, bsum, N);
  scan2_kernel<<<1, 1024, 0, stream>>>(bsum, nbN);
  scan3_kernel<<<nbN, 256, 0, stream>>>(off_n, bsum, N);
  fill_kernel<<<(E + 255) / 256, 256, 0, stream>>>(ab_dst, off_n, cur_n, csr_n, E);

  // ---- fused gather + MLP for atom features (+pool) ----
  fused_mlp_kernel<1><<<(N + 31) / 32, 256, 0, stream>>>(
      node_hidden, out_edge, ab_src, off_n, deg_n, csr_n, nullptr, nullptr,
      node_hidden, node_gid, fac_node, w1t_ab, ab_b1, w2t_ab, ab_b2,
      ab_ln_g, ab_ln_b, out_node, out_graph, N);

  pooldiv_kernel<<<G, 256, 0, stream>>>(out_graph, recip_node);
}

// Round 4
// 867.819 us; speedup vs baseline: 1.3114x; 1.3114x over previous
//
#include <hip/hip_runtime.h>

#define HDIM 256
#define LNEPS 1e-5f

typedef float f32x4 __attribute__((ext_vector_type(4)));
typedef short bf16x8 __attribute__((ext_vector_type(8)));

static __device__ __forceinline__ unsigned short f2b(float f) {
  union { float f; unsigned u; } v; v.f = f;
  return (unsigned short)((v.u + 0x7fffu + ((v.u >> 16) & 1u)) >> 16);
}
static __device__ __forceinline__ unsigned pk2(float lo, float hi) {
  return (unsigned)f2b(lo) | ((unsigned)f2b(hi) << 16);
}

// ---------------- transpose + bf16 convert: in[K][N] -> out[N][K] ----------------
__global__ void cvtw_kernel(const float* __restrict__ in, unsigned short* __restrict__ out,
                            int K, int N) {
  int idx = blockIdx.x * 256 + threadIdx.x;
  if (idx >= K * N) return;
  int k = idx / N, n = idx - k * N;
  out[(size_t)n * K + k] = f2b(in[idx]);
}

// ---------------- per-graph counts ----------------
__global__ void count_kernel(const int* __restrict__ node_gid, const int* __restrict__ bond_gid,
                             int* cnt_node, int* cnt_bond, int N, int E) {
  int i = blockIdx.x * 256 + threadIdx.x;
  if (i < N) atomicAdd(&cnt_node[node_gid[i]], 1);
  if (i < E) atomicAdd(&cnt_bond[bond_gid[i]], 1);
}

__global__ void factor_kernel(const int* __restrict__ cnt_node, const int* __restrict__ cnt_bond,
                              float* fac_node, float* fac_bond, float* recip_node, int G) {
  int g = blockIdx.x * 256 + threadIdx.x;
  if (g >= G) return;
  float cn = fmaxf((float)cnt_node[g], 1.f);
  float cb = fmaxf((float)cnt_bond[g], 1.f);
  fac_node[g] = rsqrtf(cn);
  fac_bond[g] = rsqrtf(cb);
  recip_node[g] = 1.f / cn;
}

// ---------------- CSR build ----------------
__global__ void deg_kernel(const int* __restrict__ dst, int* __restrict__ deg, int n) {
  int i = blockIdx.x * 256 + threadIdx.x;
  if (i < n) atomicAdd(&deg[dst[i]], 1);
}

__global__ void scan1_kernel(const int* __restrict__ deg, int* __restrict__ excl,
                             int* __restrict__ bsum, int n) {
  int t = threadIdx.x;
  int i = blockIdx.x * 256 + t;
  int v = (i < n) ? deg[i] : 0;
  int lane = t & 63, w = t >> 6;
  int s = v;
#pragma unroll
  for (int d = 1; d < 64; d <<= 1) {
    int u = __shfl_up(s, d);
    if (lane >= d) s += u;
  }
  __shared__ int wsum[4];
  if (lane == 63) wsum[w] = s;
  __syncthreads();
  int base = 0;
  for (int ww = 0; ww < w; ++ww) base += wsum[ww];
  if (i < n) excl[i] = base + s - v;
  if (t == 255) bsum[blockIdx.x] = base + s;
}

__global__ void scan2_kernel(int* __restrict__ bsum, int nb) {
  int t = threadIdx.x;  // 1024 threads
  int v = (t < nb) ? bsum[t] : 0;
  int lane = t & 63, w = t >> 6;
  int s = v;
#pragma unroll
  for (int d = 1; d < 64; d <<= 1) {
    int u = __shfl_up(s, d);
    if (lane >= d) s += u;
  }
  __shared__ int wsum[16];
  if (lane == 63) wsum[w] = s;
  __syncthreads();
  int base = 0;
  for (int ww = 0; ww < w; ++ww) base += wsum[ww];
  if (t < nb) bsum[t] = base + s - v;
}

__global__ void scan3_kernel(int* __restrict__ excl, const int* __restrict__ bsum, int n) {
  int i = blockIdx.x * 256 + threadIdx.x;
  if (i < n) excl[i] += bsum[blockIdx.x];
}

__global__ void fill_kernel(const int* __restrict__ dst, const int* __restrict__ off,
                            int* __restrict__ cursor, int* __restrict__ csr, int n) {
  int i = blockIdx.x * 256 + threadIdx.x;
  if (i >= n) return;
  int d = dst[i];
  int p = atomicAdd(&cursor[d], 1);
  csr[off[d] + p] = i;
}

// ---------------- gather: agg_e[d] = (Σ rbf_a)@W + cnt·b + Σ edge_hidden[src_a] ----------------
__global__ __launch_bounds__(256) void angle_gather_kernel(
    const float* __restrict__ bond_angle, const int* __restrict__ ba_src,
    const float* __restrict__ edge_hidden,
    const int* __restrict__ off, const int* __restrict__ deg, const int* __restrict__ csr,
    const float* __restrict__ rbf_w, const float* __restrict__ rbf_b,
    float* __restrict__ agg_e, int E) {
  int w = threadIdx.x >> 6, lane = threadIdx.x & 63;
  int d = blockIdx.x * 4 + w;
  if (d >= E) return;
  int c4 = lane * 4;
  int start = off[d], cnt = deg[d];
  f32x4 acc = (f32x4)0.f;
  float rbfs = 0.f;
  float cc = 0.1f * (float)(lane & 31);
  for (int i = 0; i < cnt; ++i) {
    int a = csr[start + i];
    float av = bond_angle[a];
    if (lane < 32) {
      float dd = av - cc;
      rbfs += __expf(-10.f * dd * dd);
    }
    int s = ba_src[a];
    acc += *(const f32x4*)&edge_hidden[(size_t)s * HDIM + c4];
  }
#pragma unroll
  for (int k = 0; k < 32; ++k) {
    float rv = __shfl(rbfs, k);
    f32x4 wv = *(const f32x4*)&rbf_w[k * HDIM + c4];
    acc[0] += rv * wv[0]; acc[1] += rv * wv[1];
    acc[2] += rv * wv[2]; acc[3] += rv * wv[3];
  }
  f32x4 bv = *(const f32x4*)&rbf_b[c4];
  float fc = (float)cnt;
  acc[0] += fc * bv[0]; acc[1] += fc * bv[1];
  acc[2] += fc * bv[2]; acc[3] += fc * bv[3];
  *(f32x4*)&agg_e[(size_t)d * HDIM + c4] = acc;
}

// ---------------- gather: agg_n[d] = Σ (edge_out[e] + node_hidden[src_e]) ----------------
__global__ __launch_bounds__(256) void node_gather_kernel(
    const float* __restrict__ node_hidden, const float* __restrict__ edge_out,
    const int* __restrict__ ab_src,
    const int* __restrict__ off, const int* __restrict__ deg, const int* __restrict__ csr,
    float* __restrict__ agg_n, int N) {
  int w = threadIdx.x >> 6, lane = threadIdx.x & 63;
  int d = blockIdx.x * 4 + w;
  if (d >= N) return;
  int c4 = lane * 4;
  int start = off[d], cnt = deg[d];
  f32x4 acc = (f32x4)0.f;
  for (int i = 0; i < cnt; ++i) {
    int e = csr[start + i];
    int s = ab_src[e];
    f32x4 a = *(const f32x4*)&edge_out[(size_t)e * HDIM + c4];
    f32x4 b = *(const f32x4*)&node_hidden[(size_t)s * HDIM + c4];
    acc += a;
    acc += b;
  }
  *(f32x4*)&agg_n[(size_t)d * HDIM + c4] = acc;
}

// ---------------- fused MLP + LayerNorm + graph_normal + residual (+pool) ----------------
// 32 rows/block, 256 threads (4 waves), LDS 33.3KB -> 4 blocks/CU (R2-verified geometry).
// Register budget: 64 arch VGPR + 64 AGPR (acc1 32 + acc2 32) = 128/wave cap at 4
// waves/SIMD -> NO spill (R2 counters: WRITE ideal). R0's (512,4) config spilled
// ~200MB/dispatch (WRITE 332 vs 134 ideal) -- this is the fix for that.
template <int POOL>
__global__ __launch_bounds__(256, 4) void mlp_kernel(
    const float* agg_in, float* out_rows,  // may alias (in-place per-block)
    const float* __restrict__ residual, const int* __restrict__ gid,
    const float* __restrict__ gfactor,
    const unsigned short* __restrict__ w1t, const float* __restrict__ b1,
    const unsigned short* __restrict__ w2t, const float* __restrict__ b2,
    const float* __restrict__ ln_g, const float* __restrict__ ln_b,
    float* pool_out, int M) {
  __shared__ __align__(16) char smem[33280];
  char* Xb = smem;                        // bf16 [32][256] swizzled, 16KB
  char* Hb = smem + 16384;                // bf16 [32][256] (one half of H1), 16KB
  float* Outs = (float*)smem;             // f32 [32][256], overlays Xb+Hb after GEMMs
  float* fstat = (float*)(smem + 32768);  // [32][2] mean/rstd
  float* gfs = (float*)(smem + 33024);    // [32]
  int* gid_s = (int*)(smem + 33152);      // [32]

  int t = threadIdx.x;
  int row0 = blockIdx.x * 32;
  int w = t >> 6, lane = t & 63;
  int l15 = lane & 15, lg = lane >> 4;

  // ---- stage X: f32 -> bf16 LDS (swizzled); graph factors ----
  {
    int row = t >> 3;
    int c0 = (t & 7) * 32;
    int gr = row0 + row; if (gr >= M) gr = M - 1;
    const float* src = agg_in + (size_t)gr * HDIM + c0;
#pragma unroll
    for (int i = 0; i < 4; ++i) {
      f32x4 a = *(const f32x4*)(src + i * 8);
      f32x4 b = *(const f32x4*)(src + i * 8 + 4);
      int byte = (row * 512 + (c0 + i * 8) * 2) ^ ((row & 7) << 4);
      *(uint4*)(Xb + byte) =
          make_uint4(pk2(a[0], a[1]), pk2(a[2], a[3]), pk2(b[0], b[1]), pk2(b[2], b[3]));
    }
    if (t < 32) {
      int r = row0 + t;
      int g = (r < M) ? gid[r] : 0;
      gid_s[t] = g;
      gfs[t] = gfactor[g];
    }
  }
  __syncthreads();

  f32x4 acc2[2][4];  // [mt][nf] : row m = mt*16 + lg*4 + jr ; col n2 = w*64 + nf*16 + l15
#pragma unroll
  for (int mt = 0; mt < 2; ++mt)
#pragma unroll
    for (int nf = 0; nf < 4; ++nf) acc2[mt][nf] = (f32x4)0.f;

  for (int h = 0; h < 2; ++h) {
    // ---- GEMM1 (swapped): D[n1][m]; wave's n1 tiles = h*256 + w*64 + tt*16 ----
    f32x4 acc1[4][2];
#pragma unroll
    for (int tt = 0; tt < 4; ++tt)
#pragma unroll
      for (int mt = 0; mt < 2; ++mt) acc1[tt][mt] = (f32x4)0.f;

    const unsigned short* a1p = w1t + (size_t)(h * 256 + w * 64 + l15) * 256 + lg * 8;
#pragma unroll
    for (int kk = 0; kk < 8; ++kk) {
      bf16x8 xfr[2];
#pragma unroll
      for (int mt = 0; mt < 2; ++mt) {
        int m = mt * 16 + l15;
        int byte = (m * 512 + kk * 64 + lg * 16) ^ ((m & 7) << 4);
        xfr[mt] = *(const bf16x8*)(Xb + byte);
      }
#pragma unroll
      for (int tt = 0; tt < 4; ++tt) {
        bf16x8 afr = *(const bf16x8*)(a1p + tt * 16 * 256 + kk * 32);
#pragma unroll
        for (int mt = 0; mt < 2; ++mt)
          acc1[tt][mt] = __builtin_amdgcn_mfma_f32_16x16x32_bf16(afr, xfr[mt], acc1[tt][mt], 0, 0, 0);
      }
    }

    // ---- bias + relu + packed H1 store: H1[m][n1], n1 = w*64 + tt*16 + lg*4 + r ----
#pragma unroll
    for (int tt = 0; tt < 4; ++tt) {
      f32x4 b1v = *(const f32x4*)&b1[h * 256 + w * 64 + tt * 16 + lg * 4];
#pragma unroll
      for (int mt = 0; mt < 2; ++mt) {
        f32x4 v = acc1[tt][mt] + b1v;
        v[0] = fmaxf(v[0], 0.f); v[1] = fmaxf(v[1], 0.f);
        v[2] = fmaxf(v[2], 0.f); v[3] = fmaxf(v[3], 0.f);
        int m = mt * 16 + l15;
        int n1 = w * 64 + tt * 16 + lg * 4;  // within this half
        int byte = (m * 512 + n1 * 2) ^ ((m & 7) << 4);
        *(uint2*)(Hb + byte) = make_uint2(pk2(v[0], v[1]), pk2(v[2], v[3]));
      }
    }
    __syncthreads();

    // ---- GEMM2 partial: A = H1 rows (LDS), B = w2t cols (L2) ----
    const unsigned short* w2p = w2t + (size_t)(w * 64 + l15) * 512 + h * 256 + lg * 8;
#pragma unroll
    for (int kk = 0; kk < 8; ++kk) {
      bf16x8 hfr[2];
#pragma unroll
      for (int mt = 0; mt < 2; ++mt) {
        int m = mt * 16 + l15;
        int byte = (m * 512 + kk * 64 + lg * 16) ^ ((m & 7) << 4);
        hfr[mt] = *(const bf16x8*)(Hb + byte);
      }
#pragma unroll
      for (int nf = 0; nf < 4; ++nf) {
        bf16x8 wfr = *(const bf16x8*)(w2p + nf * 16 * 512 + kk * 32);
#pragma unroll
        for (int mt = 0; mt < 2; ++mt)
          acc2[mt][nf] = __builtin_amdgcn_mfma_f32_16x16x32_bf16(hfr[mt], wfr, acc2[mt][nf], 0, 0, 0);
      }
    }
    __syncthreads();
  }

  // ---- Outs = acc2 + b2 (f32 LDS) ----
#pragma unroll
  for (int nf = 0; nf < 4; ++nf) {
    float b2v = b2[w * 64 + nf * 16 + l15];
#pragma unroll
    for (int mt = 0; mt < 2; ++mt)
#pragma unroll
      for (int jr = 0; jr < 4; ++jr)
        Outs[(mt * 16 + lg * 4 + jr) * 256 + (w * 64 + nf * 16 + l15)] = acc2[mt][nf][jr] + b2v;
  }
  __syncthreads();

  // ---- LayerNorm stats: 8 threads per row ----
  {
    int row = t >> 3, sub = t & 7;
    float s = 0.f, ss = 0.f;
#pragma unroll
    for (int i = 0; i < 8; ++i) {
      f32x4 v = *(const f32x4*)&Outs[row * 256 + sub * 32 + i * 4];
      s += v[0] + v[1] + v[2] + v[3];
      ss += v[0] * v[0] + v[1] * v[1] + v[2] * v[2] + v[3] * v[3];
    }
    s += __shfl_xor(s, 1); ss += __shfl_xor(ss, 1);
    s += __shfl_xor(s, 2); ss += __shfl_xor(ss, 2);
    s += __shfl_xor(s, 4); ss += __shfl_xor(ss, 4);
    if (sub == 0) {
      float mean = s * (1.f / 256.f);
      float var = ss * (1.f / 256.f) - mean * mean;
      fstat[row * 2] = mean;
      fstat[row * 2 + 1] = rsqrtf(var + LNEPS);
    }
  }
  __syncthreads();

  // ---- finalize: LN affine, graph_normal, residual, store (+segmented pool) ----
  {
    float g_t = ln_g[t], bb_t = ln_b[t];
    float psum = 0.f;
    int curg = -1;
    for (int p = 0; p < 32; ++p) {
      int gr = row0 + p;
      if (gr < M) {
        float v = Outs[p * 256 + t];
        v = (v - fstat[p * 2]) * fstat[p * 2 + 1] * g_t + bb_t;
        v *= gfs[p];
        v += residual[(size_t)gr * HDIM + t];
        out_rows[(size_t)gr * HDIM + t] = v;
        if (POOL) {
          int g = gid_s[p];
          if (g != curg) {
            if (curg >= 0) atomicAdd(&pool_out[(size_t)curg * HDIM + t], psum);
            psum = 0.f;
            curg = g;
          }
          psum += v;
        }
      }
    }
    if (POOL && curg >= 0) atomicAdd(&pool_out[(size_t)curg * HDIM + t], psum);
  }
}

// ---------------- pooled sums -> means ----------------
__global__ void pooldiv_kernel(float* out_graph, const float* __restrict__ recip_node) {
  int g = blockIdx.x, t = threadIdx.x;
  out_graph[(size_t)g * HDIM + t] *= recip_node[g];
}

extern "C" void kernel_launch(void* const* d_in, const int* in_sizes, int n_in,
                              void* d_out, int out_size, void* d_ws, size_t ws_size,
                              hipStream_t stream) {
  const float* node_hidden = (const float*)d_in[0];
  const float* edge_hidden = (const float*)d_in[1];
  const float* bond_angle = (const float*)d_in[2];
  const int* ab_src = (const int*)d_in[3];
  const int* ab_dst = (const int*)d_in[4];
  const int* ba_src = (const int*)d_in[5];
  const int* ba_dst = (const int*)d_in[6];
  const int* node_gid = (const int*)d_in[7];
  const int* bond_gid = (const int*)d_in[8];
  const float* rbf_w = (const float*)d_in[10];
  const float* rbf_b = (const float*)d_in[11];
  const float* ba_w1 = (const float*)d_in[12];
  const float* ba_b1 = (const float*)d_in[13];
  const float* ba_w2 = (const float*)d_in[14];
  const float* ba_b2 = (const float*)d_in[15];
  const float* ba_ln_g = (const float*)d_in[16];
  const float* ba_ln_b = (const float*)d_in[17];
  const float* ab_w1 = (const float*)d_in[18];
  const float* ab_b1 = (const float*)d_in[19];
  const float* ab_w2 = (const float*)d_in[20];
  const float* ab_b2 = (const float*)d_in[21];
  const float* ab_ln_g = (const float*)d_in[22];
  const float* ab_ln_b = (const float*)d_in[23];

  int N = in_sizes[0] / HDIM;
  int E = in_sizes[1] / HDIM;
  int A = in_sizes[2];
  int G = out_size / HDIM - N - E;

  float* out_node = (float*)d_out;
  float* out_edge = out_node + (size_t)N * HDIM;
  float* out_graph = out_edge + (size_t)E * HDIM;

  // ---- workspace layout ----
  char* ws = (char*)d_ws;
  int* cnt_node = (int*)ws;                    // G   (zeroed)
  int* cnt_bond = cnt_node + G;                // G   (zeroed)
  int* deg_e = cnt_bond + G;                   // E   (zeroed)
  int* cur_e = deg_e + E;                      // E   (zeroed)
  int* deg_n = cur_e + E;                      // N   (zeroed)
  int* cur_n = deg_n + N;                      // N   (zeroed)
  size_t zero_bytes = (size_t)(2 * G + 2 * E + 2 * N) * 4;
  float* fac_node = (float*)(cur_n + N);       // G
  float* fac_bond = fac_node + G;              // G
  float* recip_node = fac_bond + G;            // G
  int* off_e = (int*)(recip_node + G);         // E
  int* csr_e = off_e + E;                      // A
  int* off_n = csr_e + A;                      // N
  int* csr_n = off_n + N;                      // E
  int* bsum = csr_n + E;                       // 1024
  size_t off = ((size_t)((char*)(bsum + 1024) - ws) + 255) & ~(size_t)255;
  unsigned short* w1t_ba = (unsigned short*)(ws + off); off += (size_t)512 * 256 * 2;
  unsigned short* w2t_ba = (unsigned short*)(ws + off); off += (size_t)256 * 512 * 2;
  unsigned short* w1t_ab = (unsigned short*)(ws + off); off += (size_t)512 * 256 * 2;
  unsigned short* w2t_ab = (unsigned short*)(ws + off); off += (size_t)256 * 512 * 2;

  hipMemsetAsync(d_ws, 0, zero_bytes, stream);
  hipMemsetAsync(out_graph, 0, (size_t)G * HDIM * 4, stream);

  int wgrid = (256 * 512 + 255) / 256;
  cvtw_kernel<<<wgrid, 256, 0, stream>>>(ba_w1, w1t_ba, 256, 512);
  cvtw_kernel<<<wgrid, 256, 0, stream>>>(ba_w2, w2t_ba, 512, 256);
  cvtw_kernel<<<wgrid, 256, 0, stream>>>(ab_w1, w1t_ab, 256, 512);
  cvtw_kernel<<<wgrid, 256, 0, stream>>>(ab_w2, w2t_ab, 512, 256);

  count_kernel<<<(E + 255) / 256, 256, 0, stream>>>(node_gid, bond_gid, cnt_node, cnt_bond, N, E);
  factor_kernel<<<(G + 255) / 256, 256, 0, stream>>>(cnt_node, cnt_bond, fac_node, fac_bond,
                                                     recip_node, G);

  // ---- CSR for bond-angle graph ----
  deg_kernel<<<(A + 255) / 256, 256, 0, stream>>>(ba_dst, deg_e, A);
  int nbE = (E + 255) / 256;
  scan1_kernel<<<nbE, 256, 0, stream>>>(deg_e, off_e, bsum, E);
  scan2_kernel<<<1, 1024, 0, stream>>>(bsum, nbE);
  scan3_kernel<<<nbE, 256, 0, stream>>>(off_e, bsum, E);
  fill_kernel<<<(A + 255) / 256, 256, 0, stream>>>(ba_dst, off_e, cur_e, csr_e, A);

  angle_gather_kernel<<<(E + 3) / 4, 256, 0, stream>>>(bond_angle, ba_src, edge_hidden,
                                                       off_e, deg_e, csr_e, rbf_w, rbf_b,
                                                       out_edge, E);
  mlp_kernel<0><<<(E + 31) / 32, 256, 0, stream>>>(out_edge, out_edge, edge_hidden, bond_gid,
                                                   fac_bond, w1t_ba, ba_b1, w2t_ba, ba_b2,
                                                   ba_ln_g, ba_ln_b, nullptr, E);

  // ---- CSR for atom-bond graph ----
  deg_kernel<<<(E + 255) / 256, 256, 0, stream>>>(ab_dst, deg_n, E);
  int nbN = (N + 255) / 256;
  scan1_kernel<<<nbN, 256, 0, stream>>>(deg_n, off_n, bsum, N);
  scan2_kernel<<<1, 1024, 0, stream>>>(bsum, nbN);
  scan3_kernel<<<nbN, 256, 0, stream>>>(off_n, bsum, N);
  fill_kernel<<<(E + 255) / 256, 256, 0, stream>>>(ab_dst, off_n, cur_n, csr_n, E);

  node_gather_kernel<<<(N + 3) / 4, 256, 0, stream>>>(node_hidden, out_edge, ab_src,
                                                      off_n, deg_n, csr_n, out_node, N);
  mlp_kernel<1><<<(N + 31) / 32, 256, 0, stream>>>(out_node, out_node, node_hidden, node_gid,
                                                   fac_node, w1t_ab, ab_b1, w2t_ab, ab_b2,
                                                   ab_ln_g, ab_ln_b, out_graph, N);

  pooldiv_kernel<<<G, 256, 0, stream>>>(out_graph, recip_node);
}

// Round 5
// 865.281 us; speedup vs baseline: 1.3153x; 1.0029x over previous
//
#include <hip/hip_runtime.h>

#define HDIM 256
#define LNEPS 1e-5f

typedef float f32x4 __attribute__((ext_vector_type(4)));
typedef short bf16x8 __attribute__((ext_vector_type(8)));

static __device__ __forceinline__ unsigned short f2b(float f) {
  union { float f; unsigned u; } v; v.f = f;
  return (unsigned short)((v.u + 0x7fffu + ((v.u >> 16) & 1u)) >> 16);
}
static __device__ __forceinline__ unsigned pk2(float lo, float hi) {
  return (unsigned)f2b(lo) | ((unsigned)f2b(hi) << 16);
}

// ---------------- transpose + bf16 convert: in[K][N] -> out[N][K] ----------------
__global__ void cvtw_kernel(const float* __restrict__ in, unsigned short* __restrict__ out,
                            int K, int N) {
  int idx = blockIdx.x * 256 + threadIdx.x;
  if (idx >= K * N) return;
  int k = idx / N, n = idx - k * N;
  out[(size_t)n * K + k] = f2b(in[idx]);
}

// ---------------- per-graph counts ----------------
__global__ void count_kernel(const int* __restrict__ node_gid, const int* __restrict__ bond_gid,
                             int* cnt_node, int* cnt_bond, int N, int E) {
  int i = blockIdx.x * 256 + threadIdx.x;
  if (i < N) atomicAdd(&cnt_node[node_gid[i]], 1);
  if (i < E) atomicAdd(&cnt_bond[bond_gid[i]], 1);
}

__global__ void factor_kernel(const int* __restrict__ cnt_node, const int* __restrict__ cnt_bond,
                              float* fac_node, float* fac_bond, float* recip_node, int G) {
  int g = blockIdx.x * 256 + threadIdx.x;
  if (g >= G) return;
  float cn = fmaxf((float)cnt_node[g], 1.f);
  float cb = fmaxf((float)cnt_bond[g], 1.f);
  fac_node[g] = rsqrtf(cn);
  fac_bond[g] = rsqrtf(cb);
  recip_node[g] = 1.f / cn;
}

// ---------------- CSR build ----------------
__global__ void deg_kernel(const int* __restrict__ dst, int* __restrict__ deg, int n) {
  int i = blockIdx.x * 256 + threadIdx.x;
  if (i < n) atomicAdd(&deg[dst[i]], 1);
}

__global__ void scan1_kernel(const int* __restrict__ deg, int* __restrict__ excl,
                             int* __restrict__ bsum, int n) {
  int t = threadIdx.x;
  int i = blockIdx.x * 256 + t;
  int v = (i < n) ? deg[i] : 0;
  int lane = t & 63, w = t >> 6;
  int s = v;
#pragma unroll
  for (int d = 1; d < 64; d <<= 1) {
    int u = __shfl_up(s, d);
    if (lane >= d) s += u;
  }
  __shared__ int wsum[4];
  if (lane == 63) wsum[w] = s;
  __syncthreads();
  int base = 0;
  for (int ww = 0; ww < w; ++ww) base += wsum[ww];
  if (i < n) excl[i] = base + s - v;
  if (t == 255) bsum[blockIdx.x] = base + s;
}

__global__ void scan2_kernel(int* __restrict__ bsum, int nb) {
  int t = threadIdx.x;  // 1024 threads
  int v = (t < nb) ? bsum[t] : 0;
  int lane = t & 63, w = t >> 6;
  int s = v;
#pragma unroll
  for (int d = 1; d < 64; d <<= 1) {
    int u = __shfl_up(s, d);
    if (lane >= d) s += u;
  }
  __shared__ int wsum[16];
  if (lane == 63) wsum[w] = s;
  __syncthreads();
  int base = 0;
  for (int ww = 0; ww < w; ++ww) base += wsum[ww];
  if (t < nb) bsum[t] = base + s - v;
}

__global__ void scan3_kernel(int* __restrict__ excl, const int* __restrict__ bsum, int n) {
  int i = blockIdx.x * 256 + threadIdx.x;
  if (i < n) excl[i] += bsum[blockIdx.x];
}

__global__ void fill_kernel(const int* __restrict__ dst, const int* __restrict__ off,
                            int* __restrict__ cursor, int* __restrict__ csr, int n) {
  int i = blockIdx.x * 256 + threadIdx.x;
  if (i >= n) return;
  int d = dst[i];
  int p = atomicAdd(&cursor[d], 1);
  csr[off[d] + p] = i;
}

// ---------------- gather: agg_e[d] = (Σ rbf_a)@W + cnt·b + Σ edge_hidden[src_a] ----------------
__global__ __launch_bounds__(256) void angle_gather_kernel(
    const float* __restrict__ bond_angle, const int* __restrict__ ba_src,
    const float* __restrict__ edge_hidden,
    const int* __restrict__ off, const int* __restrict__ deg, const int* __restrict__ csr,
    const float* __restrict__ rbf_w, const float* __restrict__ rbf_b,
    float* __restrict__ agg_e, int E) {
  int w = threadIdx.x >> 6, lane = threadIdx.x & 63;
  int d = blockIdx.x * 4 + w;
  if (d >= E) return;
  int c4 = lane * 4;
  int start = off[d], cnt = deg[d];
  f32x4 acc = (f32x4)0.f;
  float rbfs = 0.f;
  float cc = 0.1f * (float)(lane & 31);
  for (int i = 0; i < cnt; ++i) {
    int a = csr[start + i];
    float av = bond_angle[a];
    if (lane < 32) {
      float dd = av - cc;
      rbfs += __expf(-10.f * dd * dd);
    }
    int s = ba_src[a];
    acc += *(const f32x4*)&edge_hidden[(size_t)s * HDIM + c4];
  }
#pragma unroll
  for (int k = 0; k < 32; ++k) {
    float rv = __shfl(rbfs, k);
    f32x4 wv = *(const f32x4*)&rbf_w[k * HDIM + c4];
    acc[0] += rv * wv[0]; acc[1] += rv * wv[1];
    acc[2] += rv * wv[2]; acc[3] += rv * wv[3];
  }
  f32x4 bv = *(const f32x4*)&rbf_b[c4];
  float fc = (float)cnt;
  acc[0] += fc * bv[0]; acc[1] += fc * bv[1];
  acc[2] += fc * bv[2]; acc[3] += fc * bv[3];
  *(f32x4*)&agg_e[(size_t)d * HDIM + c4] = acc;
}

// ---------------- gather: agg_n[d] = Σ (edge_out[e] + node_hidden[src_e]) ----------------
__global__ __launch_bounds__(256) void node_gather_kernel(
    const float* __restrict__ node_hidden, const float* __restrict__ edge_out,
    const int* __restrict__ ab_src,
    const int* __restrict__ off, const int* __restrict__ deg, const int* __restrict__ csr,
    float* __restrict__ agg_n, int N) {
  int w = threadIdx.x >> 6, lane = threadIdx.x & 63;
  int d = blockIdx.x * 4 + w;
  if (d >= N) return;
  int c4 = lane * 4;
  int start = off[d], cnt = deg[d];
  f32x4 acc = (f32x4)0.f;
  for (int i = 0; i < cnt; ++i) {
    int e = csr[start + i];
    int s = ab_src[e];
    f32x4 a = *(const f32x4*)&edge_out[(size_t)e * HDIM + c4];
    f32x4 b = *(const f32x4*)&node_hidden[(size_t)s * HDIM + c4];
    acc += a;
    acc += b;
  }
  *(f32x4*)&agg_n[(size_t)d * HDIM + c4] = acc;
}

// ---------------- fused MLP + LayerNorm + graph_normal + residual (+pool) ----------------
// 32 rows/block, 256 threads (4 waves), LDS 33.3KB.
// __launch_bounds__(256,3): 3 blocks/CU, ~170 unified regs/wave = 64 AGPR (acc1+acc2)
// + ~106 arch VGPR. The extra arch VGPRs let the compiler keep ~10 weight fragments
// in flight in the unrolled kk-loops. Rounds 0-4 all clamped at 64 arch VGPRs
// ((256,4)/(512,4) cap 128 - 64 AGPR), which fully SERIALIZED the 128 weight loads
// per wave at ~800cyc L3 latency (~100k cyc/wave) -- the invariant ~330us wall.
template <int POOL>
__global__ __launch_bounds__(256, 3) void mlp_kernel(
    const float* agg_in, float* out_rows,  // may alias (in-place per-block)
    const float* __restrict__ residual, const int* __restrict__ gid,
    const float* __restrict__ gfactor,
    const unsigned short* __restrict__ w1t, const float* __restrict__ b1,
    const unsigned short* __restrict__ w2t, const float* __restrict__ b2,
    const float* __restrict__ ln_g, const float* __restrict__ ln_b,
    float* pool_out, int M) {
  __shared__ __align__(16) char smem[33280];
  char* Xb = smem;                        // bf16 [32][256] swizzled, 16KB
  char* Hb = smem + 16384;                // bf16 [32][256] (one half of H1), 16KB
  float* Outs = (float*)smem;             // f32 [32][256], overlays Xb+Hb after GEMMs
  float* fstat = (float*)(smem + 32768);  // [32][2] mean/rstd
  float* gfs = (float*)(smem + 33024);    // [32]
  int* gid_s = (int*)(smem + 33152);      // [32]

  int t = threadIdx.x;
  int row0 = blockIdx.x * 32;
  int w = t >> 6, lane = t & 63;
  int l15 = lane & 15, lg = lane >> 4;

  // ---- stage X: f32 -> bf16 LDS (swizzled); graph factors ----
  {
    int row = t >> 3;
    int c0 = (t & 7) * 32;
    int gr = row0 + row; if (gr >= M) gr = M - 1;
    const float* src = agg_in + (size_t)gr * HDIM + c0;
#pragma unroll
    for (int i = 0; i < 4; ++i) {
      f32x4 a = *(const f32x4*)(src + i * 8);
      f32x4 b = *(const f32x4*)(src + i * 8 + 4);
      int byte = (row * 512 + (c0 + i * 8) * 2) ^ ((row & 7) << 4);
      *(uint4*)(Xb + byte) =
          make_uint4(pk2(a[0], a[1]), pk2(a[2], a[3]), pk2(b[0], b[1]), pk2(b[2], b[3]));
    }
    if (t < 32) {
      int r = row0 + t;
      int g = (r < M) ? gid[r] : 0;
      gid_s[t] = g;
      gfs[t] = gfactor[g];
    }
  }
  __syncthreads();

  f32x4 acc2[2][4];  // [mt][nf] : row m = mt*16 + lg*4 + jr ; col n2 = w*64 + nf*16 + l15
#pragma unroll
  for (int mt = 0; mt < 2; ++mt)
#pragma unroll
    for (int nf = 0; nf < 4; ++nf) acc2[mt][nf] = (f32x4)0.f;

  for (int h = 0; h < 2; ++h) {
    // ---- GEMM1 (swapped): D[n1][m]; wave's n1 tiles = h*256 + w*64 + tt*16 ----
    f32x4 acc1[4][2];
#pragma unroll
    for (int tt = 0; tt < 4; ++tt)
#pragma unroll
      for (int mt = 0; mt < 2; ++mt) acc1[tt][mt] = (f32x4)0.f;

    const unsigned short* a1p = w1t + (size_t)(h * 256 + w * 64 + l15) * 256 + lg * 8;
#pragma unroll
    for (int kk = 0; kk < 8; ++kk) {
      bf16x8 xfr[2];
#pragma unroll
      for (int mt = 0; mt < 2; ++mt) {
        int m = mt * 16 + l15;
        int byte = (m * 512 + kk * 64 + lg * 16) ^ ((m & 7) << 4);
        xfr[mt] = *(const bf16x8*)(Xb + byte);
      }
#pragma unroll
      for (int tt = 0; tt < 4; ++tt) {
        bf16x8 afr = *(const bf16x8*)(a1p + tt * 16 * 256 + kk * 32);
#pragma unroll
        for (int mt = 0; mt < 2; ++mt)
          acc1[tt][mt] = __builtin_amdgcn_mfma_f32_16x16x32_bf16(afr, xfr[mt], acc1[tt][mt], 0, 0, 0);
      }
    }

    // ---- bias + relu + packed H1 store: H1[m][n1], n1 = w*64 + tt*16 + lg*4 + r ----
#pragma unroll
    for (int tt = 0; tt < 4; ++tt) {
      f32x4 b1v = *(const f32x4*)&b1[h * 256 + w * 64 + tt * 16 + lg * 4];
#pragma unroll
      for (int mt = 0; mt < 2; ++mt) {
        f32x4 v = acc1[tt][mt] + b1v;
        v[0] = fmaxf(v[0], 0.f); v[1] = fmaxf(v[1], 0.f);
        v[2] = fmaxf(v[2], 0.f); v[3] = fmaxf(v[3], 0.f);
        int m = mt * 16 + l15;
        int n1 = w * 64 + tt * 16 + lg * 4;  // within this half
        int byte = (m * 512 + n1 * 2) ^ ((m & 7) << 4);
        *(uint2*)(Hb + byte) = make_uint2(pk2(v[0], v[1]), pk2(v[2], v[3]));
      }
    }
    __syncthreads();

    // ---- GEMM2 partial: A = H1 rows (LDS), B = w2t cols (L2) ----
    const unsigned short* w2p = w2t + (size_t)(w * 64 + l15) * 512 + h * 256 + lg * 8;
#pragma unroll
    for (int kk = 0; kk < 8; ++kk) {
      bf16x8 hfr[2];
#pragma unroll
      for (int mt = 0; mt < 2; ++mt) {
        int m = mt * 16 + l15;
        int byte = (m * 512 + kk * 64 + lg * 16) ^ ((m & 7) << 4);
        hfr[mt] = *(const bf16x8*)(Hb + byte);
      }
#pragma unroll
      for (int nf = 0; nf < 4; ++nf) {
        bf16x8 wfr = *(const bf16x8*)(w2p + nf * 16 * 512 + kk * 32);
#pragma unroll
        for (int mt = 0; mt < 2; ++mt)
          acc2[mt][nf] = __builtin_amdgcn_mfma_f32_16x16x32_bf16(hfr[mt], wfr, acc2[mt][nf], 0, 0, 0);
      }
    }
    __syncthreads();
  }

  // ---- Outs = acc2 + b2 (f32 LDS) ----
#pragma unroll
  for (int nf = 0; nf < 4; ++nf) {
    float b2v = b2[w * 64 + nf * 16 + l15];
#pragma unroll
    for (int mt = 0; mt < 2; ++mt)
#pragma unroll
      for (int jr = 0; jr < 4; ++jr)
        Outs[(mt * 16 + lg * 4 + jr) * 256 + (w * 64 + nf * 16 + l15)] = acc2[mt][nf][jr] + b2v;
  }
  __syncthreads();

  // ---- LayerNorm stats: 8 threads per row ----
  {
    int row = t >> 3, sub = t & 7;
    float s = 0.f, ss = 0.f;
#pragma unroll
    for (int i = 0; i < 8; ++i) {
      f32x4 v = *(const f32x4*)&Outs[row * 256 + sub * 32 + i * 4];
      s += v[0] + v[1] + v[2] + v[3];
      ss += v[0] * v[0] + v[1] * v[1] + v[2] * v[2] + v[3] * v[3];
    }
    s += __shfl_xor(s, 1); ss += __shfl_xor(ss, 1);
    s += __shfl_xor(s, 2); ss += __shfl_xor(ss, 2);
    s += __shfl_xor(s, 4); ss += __shfl_xor(ss, 4);
    if (sub == 0) {
      float mean = s * (1.f / 256.f);
      float var = ss * (1.f / 256.f) - mean * mean;
      fstat[row * 2] = mean;
      fstat[row * 2 + 1] = rsqrtf(var + LNEPS);
    }
  }
  __syncthreads();

  // ---- finalize: LN affine, graph_normal, residual, store (+segmented pool) ----
  {
    float g_t = ln_g[t], bb_t = ln_b[t];
    float psum = 0.f;
    int curg = -1;
#pragma unroll 4
    for (int p = 0; p < 32; ++p) {
      int gr = row0 + p;
      if (gr < M) {
        float v = Outs[p * 256 + t];
        v = (v - fstat[p * 2]) * fstat[p * 2 + 1] * g_t + bb_t;
        v *= gfs[p];
        v += residual[(size_t)gr * HDIM + t];
        out_rows[(size_t)gr * HDIM + t] = v;
        if (POOL) {
          int g = gid_s[p];
          if (g != curg) {
            if (curg >= 0) atomicAdd(&pool_out[(size_t)curg * HDIM + t], psum);
            psum = 0.f;
            curg = g;
          }
          psum += v;
        }
      }
    }
    if (POOL && curg >= 0) atomicAdd(&pool_out[(size_t)curg * HDIM + t], psum);
  }
}

// ---------------- pooled sums -> means ----------------
__global__ void pooldiv_kernel(float* out_graph, const float* __restrict__ recip_node) {
  int g = blockIdx.x, t = threadIdx.x;
  out_graph[(size_t)g * HDIM + t] *= recip_node[g];
}

extern "C" void kernel_launch(void* const* d_in, const int* in_sizes, int n_in,
                              void* d_out, int out_size, void* d_ws, size_t ws_size,
                              hipStream_t stream) {
  const float* node_hidden = (const float*)d_in[0];
  const float* edge_hidden = (const float*)d_in[1];
  const float* bond_angle = (const float*)d_in[2];
  const int* ab_src = (const int*)d_in[3];
  const int* ab_dst = (const int*)d_in[4];
  const int* ba_src = (const int*)d_in[5];
  const int* ba_dst = (const int*)d_in[6];
  const int* node_gid = (const int*)d_in[7];
  const int* bond_gid = (const int*)d_in[8];
  const float* rbf_w = (const float*)d_in[10];
  const float* rbf_b = (const float*)d_in[11];
  const float* ba_w1 = (const float*)d_in[12];
  const float* ba_b1 = (const float*)d_in[13];
  const float* ba_w2 = (const float*)d_in[14];
  const float* ba_b2 = (const float*)d_in[15];
  const float* ba_ln_g = (const float*)d_in[16];
  const float* ba_ln_b = (const float*)d_in[17];
  const float* ab_w1 = (const float*)d_in[18];
  const float* ab_b1 = (const float*)d_in[19];
  const float* ab_w2 = (const float*)d_in[20];
  const float* ab_b2 = (const float*)d_in[21];
  const float* ab_ln_g = (const float*)d_in[22];
  const float* ab_ln_b = (const float*)d_in[23];

  int N = in_sizes[0] / HDIM;
  int E = in_sizes[1] / HDIM;
  int A = in_sizes[2];
  int G = out_size / HDIM - N - E;

  float* out_node = (float*)d_out;
  float* out_edge = out_node + (size_t)N * HDIM;
  float* out_graph = out_edge + (size_t)E * HDIM;

  // ---- workspace layout ----
  char* ws = (char*)d_ws;
  int* cnt_node = (int*)ws;                    // G   (zeroed)
  int* cnt_bond = cnt_node + G;                // G   (zeroed)
  int* deg_e = cnt_bond + G;                   // E   (zeroed)
  int* cur_e = deg_e + E;                      // E   (zeroed)
  int* deg_n = cur_e + E;                      // N   (zeroed)
  int* cur_n = deg_n + N;                      // N   (zeroed)
  size_t zero_bytes = (size_t)(2 * G + 2 * E + 2 * N) * 4;
  float* fac_node = (float*)(cur_n + N);       // G
  float* fac_bond = fac_node + G;              // G
  float* recip_node = fac_bond + G;            // G
  int* off_e = (int*)(recip_node + G);         // E
  int* csr_e = off_e + E;                      // A
  int* off_n = csr_e + A;                      // N
  int* csr_n = off_n + N;                      // E
  int* bsum = csr_n + E;                       // 1024
  size_t off = ((size_t)((char*)(bsum + 1024) - ws) + 255) & ~(size_t)255;
  unsigned short* w1t_ba = (unsigned short*)(ws + off); off += (size_t)512 * 256 * 2;
  unsigned short* w2t_ba = (unsigned short*)(ws + off); off += (size_t)256 * 512 * 2;
  unsigned short* w1t_ab = (unsigned short*)(ws + off); off += (size_t)512 * 256 * 2;
  unsigned short* w2t_ab = (unsigned short*)(ws + off); off += (size_t)256 * 512 * 2;

  hipMemsetAsync(d_ws, 0, zero_bytes, stream);
  hipMemsetAsync(out_graph, 0, (size_t)G * HDIM * 4, stream);

  int wgrid = (256 * 512 + 255) / 256;
  cvtw_kernel<<<wgrid, 256, 0, stream>>>(ba_w1, w1t_ba, 256, 512);
  cvtw_kernel<<<wgrid, 256, 0, stream>>>(ba_w2, w2t_ba, 512, 256);
  cvtw_kernel<<<wgrid, 256, 0, stream>>>(ab_w1, w1t_ab, 256, 512);
  cvtw_kernel<<<wgrid, 256, 0, stream>>>(ab_w2, w2t_ab, 512, 256);

  count_kernel<<<(E + 255) / 256, 256, 0, stream>>>(node_gid, bond_gid, cnt_node, cnt_bond, N, E);
  factor_kernel<<<(G + 255) / 256, 256, 0, stream>>>(cnt_node, cnt_bond, fac_node, fac_bond,
                                                     recip_node, G);

  // ---- CSR for bond-angle graph ----
  deg_kernel<<<(A + 255) / 256, 256, 0, stream>>>(ba_dst, deg_e, A);
  int nbE = (E + 255) / 256;
  scan1_kernel<<<nbE, 256, 0, stream>>>(deg_e, off_e, bsum, E);
  scan2_kernel<<<1, 1024, 0, stream>>>(bsum, nbE);
  scan3_kernel<<<nbE, 256, 0, stream>>>(off_e, bsum, E);
  fill_kernel<<<(A + 255) / 256, 256, 0, stream>>>(ba_dst, off_e, cur_e, csr_e, A);

  angle_gather_kernel<<<(E + 3) / 4, 256, 0, stream>>>(bond_angle, ba_src, edge_hidden,
                                                       off_e, deg_e, csr_e, rbf_w, rbf_b,
                                                       out_edge, E);
  mlp_kernel<0><<<(E + 31) / 32, 256, 0, stream>>>(out_edge, out_edge, edge_hidden, bond_gid,
                                                   fac_bond, w1t_ba, ba_b1, w2t_ba, ba_b2,
                                                   ba_ln_g, ba_ln_b, nullptr, E);

  // ---- CSR for atom-bond graph ----
  deg_kernel<<<(E + 255) / 256, 256, 0, stream>>>(ab_dst, deg_n, E);
  int nbN = (N + 255) / 256;
  scan1_kernel<<<nbN, 256, 0, stream>>>(deg_n, off_n, bsum, N);
  scan2_kernel<<<1, 1024, 0, stream>>>(bsum, nbN);
  scan3_kernel<<<nbN, 256, 0, stream>>>(off_n, bsum, N);
  fill_kernel<<<(E + 255) / 256, 256, 0, stream>>>(ab_dst, off_n, cur_n, csr_n, E);

  node_gather_kernel<<<(N + 3) / 4, 256, 0, stream>>>(node_hidden, out_edge, ab_src,
                                                      off_n, deg_n, csr_n, out_node, N);
  mlp_kernel<1><<<(N + 31) / 32, 256, 0, stream>>>(out_node, out_node, node_hidden, node_gid,
                                                   fac_node, w1t_ab, ab_b1, w2t_ab, ab_b2,
                                                   ab_ln_g, ab_ln_b, out_graph, N);

  pooldiv_kernel<<<G, 256, 0, stream>>>(out_graph, recip_node);
}

// Round 6
// 724.382 us; speedup vs baseline: 1.5711x; 1.1945x over previous
//
#include <hip/hip_runtime.h>

#define HDIM 256
#define LNEPS 1e-5f

typedef float f32x4 __attribute__((ext_vector_type(4)));
typedef short bf16x8 __attribute__((ext_vector_type(8)));

static __device__ __forceinline__ unsigned short f2b(float f) {
  union { float f; unsigned u; } v; v.f = f;
  return (unsigned short)((v.u + 0x7fffu + ((v.u >> 16) & 1u)) >> 16);
}
static __device__ __forceinline__ unsigned pk2(float lo, float hi) {
  return (unsigned)f2b(lo) | ((unsigned)f2b(hi) << 16);
}

// ---------------- weight repack into 8KB fragment-ordered slabs ----------------
// w1 [256 k][512 n1] -> slabs (h,kk): 128 n1-rows x 32 k. Element order within slab:
// ((n1l*4 + kc)*8 + ke), fragment = 8 consecutive k. 32 slabs x 4096 elem.
__global__ void pack1_kernel(const float* __restrict__ in, unsigned short* __restrict__ out) {
  int o = blockIdx.x * 256 + threadIdx.x;  // 131072
  int ke = o & 7, kc = (o >> 3) & 3, n1l = (o >> 5) & 127, sl = o >> 12;
  int h = sl >> 3, kk = sl & 7;
  int k = kk * 32 + kc * 8 + ke, n1 = h * 128 + n1l;
  out[o] = f2b(in[k * 512 + n1]);
}

// w2 [512 k2][256 n2] -> slabs (h,h2,kk2): 128 n2-rows x 32 k2.
__global__ void pack2_kernel(const float* __restrict__ in, unsigned short* __restrict__ out) {
  int o = blockIdx.x * 256 + threadIdx.x;  // 131072
  int ke = o & 7, kc = (o >> 3) & 3, n2l = (o >> 5) & 127, sl = o >> 12;
  int h = sl >> 3, r = sl & 7, h2 = r >> 2, kk2 = r & 3;
  int k2 = h * 128 + kk2 * 32 + kc * 8 + ke, n2 = h2 * 128 + n2l;
  out[o] = f2b(in[k2 * 256 + n2]);
}

// ---------------- per-graph counts ----------------
__global__ void count_kernel(const int* __restrict__ node_gid, const int* __restrict__ bond_gid,
                             int* cnt_node, int* cnt_bond, int N, int E) {
  int i = blockIdx.x * 256 + threadIdx.x;
  if (i < N) atomicAdd(&cnt_node[node_gid[i]], 1);
  if (i < E) atomicAdd(&cnt_bond[bond_gid[i]], 1);
}

__global__ void factor_kernel(const int* __restrict__ cnt_node, const int* __restrict__ cnt_bond,
                              float* fac_node, float* fac_bond, float* recip_node, int G) {
  int g = blockIdx.x * 256 + threadIdx.x;
  if (g >= G) return;
  float cn = fmaxf((float)cnt_node[g], 1.f);
  float cb = fmaxf((float)cnt_bond[g], 1.f);
  fac_node[g] = rsqrtf(cn);
  fac_bond[g] = rsqrtf(cb);
  recip_node[g] = 1.f / cn;
}

// ---------------- CSR build ----------------
__global__ void deg_kernel(const int* __restrict__ dst, int* __restrict__ deg, int n) {
  int i = blockIdx.x * 256 + threadIdx.x;
  if (i < n) atomicAdd(&deg[dst[i]], 1);
}

__global__ void scan1_kernel(const int* __restrict__ deg, int* __restrict__ excl,
                             int* __restrict__ bsum, int n) {
  int t = threadIdx.x;
  int i = blockIdx.x * 256 + t;
  int v = (i < n) ? deg[i] : 0;
  int lane = t & 63, w = t >> 6;
  int s = v;
#pragma unroll
  for (int d = 1; d < 64; d <<= 1) {
    int u = __shfl_up(s, d);
    if (lane >= d) s += u;
  }
  __shared__ int wsum[4];
  if (lane == 63) wsum[w] = s;
  __syncthreads();
  int base = 0;
  for (int ww = 0; ww < w; ++ww) base += wsum[ww];
  if (i < n) excl[i] = base + s - v;
  if (t == 255) bsum[blockIdx.x] = base + s;
}

__global__ void scan2_kernel(int* __restrict__ bsum, int nb) {
  int t = threadIdx.x;  // 1024 threads
  int v = (t < nb) ? bsum[t] : 0;
  int lane = t & 63, w = t >> 6;
  int s = v;
#pragma unroll
  for (int d = 1; d < 64; d <<= 1) {
    int u = __shfl_up(s, d);
    if (lane >= d) s += u;
  }
  __shared__ int wsum[16];
  if (lane == 63) wsum[w] = s;
  __syncthreads();
  int base = 0;
  for (int ww = 0; ww < w; ++ww) base += wsum[ww];
  if (t < nb) bsum[t] = base + s - v;
}

__global__ void scan3_kernel(int* __restrict__ excl, const int* __restrict__ bsum, int n) {
  int i = blockIdx.x * 256 + threadIdx.x;
  if (i < n) excl[i] += bsum[blockIdx.x];
}

__global__ void fill_kernel(const int* __restrict__ dst, const int* __restrict__ off,
                            int* __restrict__ cursor, int* __restrict__ csr, int n) {
  int i = blockIdx.x * 256 + threadIdx.x;
  if (i >= n) return;
  int d = dst[i];
  int p = atomicAdd(&cursor[d], 1);
  csr[off[d] + p] = i;
}

// ---------------- gather: agg_e[d] = (Σ rbf_a)@W + cnt·b + Σ edge_hidden[src_a] ----------------
__global__ __launch_bounds__(256) void angle_gather_kernel(
    const float* __restrict__ bond_angle, const int* __restrict__ ba_src,
    const float* __restrict__ edge_hidden,
    const int* __restrict__ off, const int* __restrict__ deg, const int* __restrict__ csr,
    const float* __restrict__ rbf_w, const float* __restrict__ rbf_b,
    float* __restrict__ agg_e, int E) {
  int w = threadIdx.x >> 6, lane = threadIdx.x & 63;
  int d = blockIdx.x * 4 + w;
  if (d >= E) return;
  int c4 = lane * 4;
  int start = off[d], cnt = deg[d];
  f32x4 acc = (f32x4)0.f;
  float rbfs = 0.f;
  float cc = 0.1f * (float)(lane & 31);
  for (int i = 0; i < cnt; ++i) {
    int a = csr[start + i];
    float av = bond_angle[a];
    if (lane < 32) {
      float dd = av - cc;
      rbfs += __expf(-10.f * dd * dd);
    }
    int s = ba_src[a];
    acc += *(const f32x4*)&edge_hidden[(size_t)s * HDIM + c4];
  }
#pragma unroll
  for (int k = 0; k < 32; ++k) {
    float rv = __shfl(rbfs, k);
    f32x4 wv = *(const f32x4*)&rbf_w[k * HDIM + c4];
    acc[0] += rv * wv[0]; acc[1] += rv * wv[1];
    acc[2] += rv * wv[2]; acc[3] += rv * wv[3];
  }
  f32x4 bv = *(const f32x4*)&rbf_b[c4];
  float fc = (float)cnt;
  acc[0] += fc * bv[0]; acc[1] += fc * bv[1];
  acc[2] += fc * bv[2]; acc[3] += fc * bv[3];
  *(f32x4*)&agg_e[(size_t)d * HDIM + c4] = acc;
}

// ---------------- gather: agg_n[d] = Σ (edge_out[e] + node_hidden[src_e]) ----------------
__global__ __launch_bounds__(256) void node_gather_kernel(
    const float* __restrict__ node_hidden, const float* __restrict__ edge_out,
    const int* __restrict__ ab_src,
    const int* __restrict__ off, const int* __restrict__ deg, const int* __restrict__ csr,
    float* __restrict__ agg_n, int N) {
  int w = threadIdx.x >> 6, lane = threadIdx.x & 63;
  int d = blockIdx.x * 4 + w;
  if (d >= N) return;
  int c4 = lane * 4;
  int start = off[d], cnt = deg[d];
  f32x4 acc = (f32x4)0.f;
  for (int i = 0; i < cnt; ++i) {
    int e = csr[start + i];
    int s = ab_src[e];
    f32x4 a = *(const f32x4*)&edge_out[(size_t)e * HDIM + c4];
    f32x4 b = *(const f32x4*)&node_hidden[(size_t)s * HDIM + c4];
    acc += a;
    acc += b;
  }
  *(f32x4*)&agg_n[(size_t)d * HDIM + c4] = acc;
}

// ---------------- fused MLP + LayerNorm + graph_normal + residual (+pool) ----------------
// 32 rows/block, 256 threads (4 waves), LDS 40960B exact -> 4 blocks/CU.
// Canonical §5 pipeline for WEIGHTS: 64 slab-steps (4 H-quarters x [8 G1 + 8 G2]),
// 8KB pre-packed slabs double-buffered in LDS via reg-staging (issue slab s+1 loads
// BEFORE computing slab s; ds_write after MFMAs; one barrier/step). Replaces the
// per-lane weight streaming that serialized ~128 loads/wave (the ~330us invariant
// of rounds 0-5: ~7-14 loads in flight per SIMD, everything else idle).
template <int POOL>
__global__ __launch_bounds__(256, 4) void mlp_kernel(
    const float* agg_in, float* out_rows,  // may alias (in-place per-block)
    const float* __restrict__ residual, const int* __restrict__ gid,
    const float* __restrict__ gfactor,
    const unsigned short* __restrict__ w1p, const float* __restrict__ b1,
    const unsigned short* __restrict__ w2p, const float* __restrict__ b2,
    const float* __restrict__ ln_g, const float* __restrict__ ln_b,
    float* pool_out, int M) {
  __shared__ __align__(16) char smem[40960];
  char* Xb = smem;                         // bf16 [32][256] swizzled, 16KB
  char* Hb = smem + 16384;                 // bf16 [32][128] quarter, swizzled, 8KB
  char* Wb = smem + 24576;                 // 2 x 8KB weight-slab double buffer
  float* Outs = (float*)smem;              // f32 [32][256], overlays Xb+Hb+Wb[0] post-GEMM
  float* fstat = (float*)(smem + 40448);   // [32][2] mean/rstd (in dead Wb[1] tail)
  float* gfs = (float*)(smem + 40704);     // [32]
  int* gid_s = (int*)(smem + 40832);       // [32]

  int t = threadIdx.x;
  int row0 = blockIdx.x * 32;
  int w = t >> 6, lane = t & 63;
  int l15 = lane & 15, lg = lane >> 4;

  auto slab_ptr = [&](int ss) -> const uint4* {
    int hh = ss >> 4, r = ss & 15;
    const unsigned short* p = (r < 8) ? (w1p + (size_t)(hh * 8 + r) * 4096)
                                      : (w2p + (size_t)(hh * 8 + (r - 8)) * 4096);
    return (const uint4*)p;
  };

  // ---- prologue: stage X (f32 -> bf16 swizzled) + slab 0 ----
  {
    const uint4* g0 = slab_ptr(0);
    uint4 s0a = g0[t], s0b = g0[t + 256];
    int row = t >> 3;
    int c0 = (t & 7) * 32;
    int gr = row0 + row; if (gr >= M) gr = M - 1;
    const float* src = agg_in + (size_t)gr * HDIM + c0;
#pragma unroll
    for (int i = 0; i < 4; ++i) {
      f32x4 a = *(const f32x4*)(src + i * 8);
      f32x4 b = *(const f32x4*)(src + i * 8 + 4);
      int byte = (row * 512 + (c0 + i * 8) * 2) ^ ((row & 7) << 4);
      *(uint4*)(Xb + byte) =
          make_uint4(pk2(a[0], a[1]), pk2(a[2], a[3]), pk2(b[0], b[1]), pk2(b[2], b[3]));
    }
    *(uint4*)(Wb + t * 16) = s0a;
    *(uint4*)(Wb + (t + 256) * 16) = s0b;
  }
  __syncthreads();

  f32x4 acc2[2][4];  // [mt][h2*2+nf] : row = mt*16+lg*4+jr ; col = h2*128+w*32+nf*16+l15
#pragma unroll
  for (int mt = 0; mt < 2; ++mt)
#pragma unroll
    for (int nf = 0; nf < 4; ++nf) acc2[mt][nf] = (f32x4)0.f;

  int s = 0;
  for (int h = 0; h < 4; ++h) {
    f32x4 acc1[2][2];  // [tt][mt]
#pragma unroll
    for (int tt = 0; tt < 2; ++tt)
#pragma unroll
      for (int mt = 0; mt < 2; ++mt) acc1[tt][mt] = (f32x4)0.f;

    // ---- GEMM1 quarter: n1 = h*128 + w*32 + tt*16 + l15, k = kk*32 + lg*8 ----
    for (int kk = 0; kk < 8; ++kk) {
      uint4 wr0, wr1;
      bool pf = (s < 63);
      if (pf) { const uint4* g = slab_ptr(s + 1); wr0 = g[t]; wr1 = g[t + 256]; }
      const char* buf = Wb + (s & 1) * 8192;
      bf16x8 xfr[2], afr[2];
#pragma unroll
      for (int mt = 0; mt < 2; ++mt) {
        int m = mt * 16 + l15;
        int byte = (m * 512 + kk * 64 + lg * 16) ^ ((m & 7) << 4);
        xfr[mt] = *(const bf16x8*)(Xb + byte);
      }
#pragma unroll
      for (int tt = 0; tt < 2; ++tt)
        afr[tt] = *(const bf16x8*)(buf + ((w * 32 + tt * 16 + l15) * 4 + lg) * 16);
#pragma unroll
      for (int tt = 0; tt < 2; ++tt)
#pragma unroll
        for (int mt = 0; mt < 2; ++mt)
          acc1[tt][mt] = __builtin_amdgcn_mfma_f32_16x16x32_bf16(afr[tt], xfr[mt], acc1[tt][mt], 0, 0, 0);

      if (kk == 7) {
        // bias + relu + packed Hb store: Hb[m][n1l], n1l = w*32 + tt*16 + lg*4 (+0..3)
#pragma unroll
        for (int tt = 0; tt < 2; ++tt) {
          f32x4 b1v = *(const f32x4*)&b1[h * 128 + w * 32 + tt * 16 + lg * 4];
#pragma unroll
          for (int mt = 0; mt < 2; ++mt) {
            f32x4 v = acc1[tt][mt] + b1v;
            v[0] = fmaxf(v[0], 0.f); v[1] = fmaxf(v[1], 0.f);
            v[2] = fmaxf(v[2], 0.f); v[3] = fmaxf(v[3], 0.f);
            int m = mt * 16 + l15;
            int n1l = w * 32 + tt * 16 + lg * 4;
            int byte = (m * 256 + n1l * 2) ^ ((m & 7) << 4);
            *(uint2*)(Hb + byte) = make_uint2(pk2(v[0], v[1]), pk2(v[2], v[3]));
          }
        }
      }
      if (pf) {
        char* nb = Wb + ((s + 1) & 1) * 8192;
        *(uint4*)(nb + t * 16) = wr0;
        *(uint4*)(nb + (t + 256) * 16) = wr1;
      }
      __syncthreads();
      ++s;
    }

    // ---- GEMM2 partial: n2 = h2*128 + w*32 + nf*16 + l15, k2-local = kk2*32 + lg*8 ----
#pragma unroll
    for (int h2 = 0; h2 < 2; ++h2) {
#pragma unroll
      for (int kk2 = 0; kk2 < 4; ++kk2) {
        uint4 wr0, wr1;
        bool pf = (s < 63);
        if (pf) { const uint4* g = slab_ptr(s + 1); wr0 = g[t]; wr1 = g[t + 256]; }
        const char* buf = Wb + (s & 1) * 8192;
        bf16x8 hfr[2], wfr[2];
#pragma unroll
        for (int mt = 0; mt < 2; ++mt) {
          int m = mt * 16 + l15;
          int byte = (m * 256 + kk2 * 64 + lg * 16) ^ ((m & 7) << 4);
          hfr[mt] = *(const bf16x8*)(Hb + byte);
        }
#pragma unroll
        for (int nf = 0; nf < 2; ++nf)
          wfr[nf] = *(const bf16x8*)(buf + ((w * 32 + nf * 16 + l15) * 4 + lg) * 16);
#pragma unroll
        for (int mt = 0; mt < 2; ++mt)
#pragma unroll
          for (int nf = 0; nf < 2; ++nf)
            acc2[mt][h2 * 2 + nf] =
                __builtin_amdgcn_mfma_f32_16x16x32_bf16(hfr[mt], wfr[nf], acc2[mt][h2 * 2 + nf], 0, 0, 0);
        if (pf) {
          char* nb = Wb + ((s + 1) & 1) * 8192;
          *(uint4*)(nb + t * 16) = wr0;
          *(uint4*)(nb + (t + 256) * 16) = wr1;
        }
        __syncthreads();
        ++s;
      }
    }
  }

  // ---- Outs = acc2 + b2 (f32 LDS); graph factors (post-GEMM: stats region now dead) ----
#pragma unroll
  for (int nf = 0; nf < 4; ++nf) {
    int col = (nf >> 1) * 128 + w * 32 + (nf & 1) * 16 + l15;
    float b2v = b2[col];
#pragma unroll
    for (int mt = 0; mt < 2; ++mt)
#pragma unroll
      for (int jr = 0; jr < 4; ++jr)
        Outs[(mt * 16 + lg * 4 + jr) * 256 + col] = acc2[mt][nf][jr] + b2v;
  }
  if (t < 32) {
    int r = row0 + t;
    int g = (r < M) ? gid[r] : 0;
    gid_s[t] = g;
    gfs[t] = gfactor[g];
  }
  __syncthreads();

  // ---- LayerNorm stats: 8 threads per row ----
  {
    int row = t >> 3, sub = t & 7;
    float ssum = 0.f, ss = 0.f;
#pragma unroll
    for (int i = 0; i < 8; ++i) {
      f32x4 v = *(const f32x4*)&Outs[row * 256 + sub * 32 + i * 4];
      ssum += v[0] + v[1] + v[2] + v[3];
      ss += v[0] * v[0] + v[1] * v[1] + v[2] * v[2] + v[3] * v[3];
    }
    ssum += __shfl_xor(ssum, 1); ss += __shfl_xor(ss, 1);
    ssum += __shfl_xor(ssum, 2); ss += __shfl_xor(ss, 2);
    ssum += __shfl_xor(ssum, 4); ss += __shfl_xor(ss, 4);
    if (sub == 0) {
      float mean = ssum * (1.f / 256.f);
      float var = ss * (1.f / 256.f) - mean * mean;
      fstat[row * 2] = mean;
      fstat[row * 2 + 1] = rsqrtf(var + LNEPS);
    }
  }
  __syncthreads();

  // ---- finalize: LN affine, graph_normal, residual, store (+segmented pool) ----
  {
    float g_t = ln_g[t], bb_t = ln_b[t];
    float psum = 0.f;
    int curg = -1;
#pragma unroll 4
    for (int p = 0; p < 32; ++p) {
      int gr = row0 + p;
      if (gr < M) {
        float v = Outs[p * 256 + t];
        v = (v - fstat[p * 2]) * fstat[p * 2 + 1] * g_t + bb_t;
        v *= gfs[p];
        v += residual[(size_t)gr * HDIM + t];
        out_rows[(size_t)gr * HDIM + t] = v;
        if (POOL) {
          int g = gid_s[p];
          if (g != curg) {
            if (curg >= 0) atomicAdd(&pool_out[(size_t)curg * HDIM + t], psum);
            psum = 0.f;
            curg = g;
          }
          psum += v;
        }
      }
    }
    if (POOL && curg >= 0) atomicAdd(&pool_out[(size_t)curg * HDIM + t], psum);
  }
}

// ---------------- pooled sums -> means ----------------
__global__ void pooldiv_kernel(float* out_graph, const float* __restrict__ recip_node) {
  int g = blockIdx.x, t = threadIdx.x;
  out_graph[(size_t)g * HDIM + t] *= recip_node[g];
}

extern "C" void kernel_launch(void* const* d_in, const int* in_sizes, int n_in,
                              void* d_out, int out_size, void* d_ws, size_t ws_size,
                              hipStream_t stream) {
  const float* node_hidden = (const float*)d_in[0];
  const float* edge_hidden = (const float*)d_in[1];
  const float* bond_angle = (const float*)d_in[2];
  const int* ab_src = (const int*)d_in[3];
  const int* ab_dst = (const int*)d_in[4];
  const int* ba_src = (const int*)d_in[5];
  const int* ba_dst = (const int*)d_in[6];
  const int* node_gid = (const int*)d_in[7];
  const int* bond_gid = (const int*)d_in[8];
  const float* rbf_w = (const float*)d_in[10];
  const float* rbf_b = (const float*)d_in[11];
  const float* ba_w1 = (const float*)d_in[12];
  const float* ba_b1 = (const float*)d_in[13];
  const float* ba_w2 = (const float*)d_in[14];
  const float* ba_b2 = (const float*)d_in[15];
  const float* ba_ln_g = (const float*)d_in[16];
  const float* ba_ln_b = (const float*)d_in[17];
  const float* ab_w1 = (const float*)d_in[18];
  const float* ab_b1 = (const float*)d_in[19];
  const float* ab_w2 = (const float*)d_in[20];
  const float* ab_b2 = (const float*)d_in[21];
  const float* ab_ln_g = (const float*)d_in[22];
  const float* ab_ln_b = (const float*)d_in[23];

  int N = in_sizes[0] / HDIM;
  int E = in_sizes[1] / HDIM;
  int A = in_sizes[2];
  int G = out_size / HDIM - N - E;

  float* out_node = (float*)d_out;
  float* out_edge = out_node + (size_t)N * HDIM;
  float* out_graph = out_edge + (size_t)E * HDIM;

  // ---- workspace layout ----
  char* ws = (char*)d_ws;
  int* cnt_node = (int*)ws;                    // G   (zeroed)
  int* cnt_bond = cnt_node + G;                // G   (zeroed)
  int* deg_e = cnt_bond + G;                   // E   (zeroed)
  int* cur_e = deg_e + E;                      // E   (zeroed)
  int* deg_n = cur_e + E;                      // N   (zeroed)
  int* cur_n = deg_n + N;                      // N   (zeroed)
  size_t zero_bytes = (size_t)(2 * G + 2 * E + 2 * N) * 4;
  float* fac_node = (float*)(cur_n + N);       // G
  float* fac_bond = fac_node + G;              // G
  float* recip_node = fac_bond + G;            // G
  int* off_e = (int*)(recip_node + G);         // E
  int* csr_e = off_e + E;                      // A
  int* off_n = csr_e + A;                      // N
  int* csr_n = off_n + N;                      // E
  int* bsum = csr_n + E;                       // 1024
  size_t off = ((size_t)((char*)(bsum + 1024) - ws) + 255) & ~(size_t)255;
  unsigned short* w1p_ba = (unsigned short*)(ws + off); off += (size_t)512 * 256 * 2;
  unsigned short* w2p_ba = (unsigned short*)(ws + off); off += (size_t)256 * 512 * 2;
  unsigned short* w1p_ab = (unsigned short*)(ws + off); off += (size_t)512 * 256 * 2;
  unsigned short* w2p_ab = (unsigned short*)(ws + off); off += (size_t)256 * 512 * 2;

  hipMemsetAsync(d_ws, 0, zero_bytes, stream);
  hipMemsetAsync(out_graph, 0, (size_t)G * HDIM * 4, stream);

  pack1_kernel<<<512, 256, 0, stream>>>(ba_w1, w1p_ba);
  pack2_kernel<<<512, 256, 0, stream>>>(ba_w2, w2p_ba);
  pack1_kernel<<<512, 256, 0, stream>>>(ab_w1, w1p_ab);
  pack2_kernel<<<512, 256, 0, stream>>>(ab_w2, w2p_ab);

  count_kernel<<<(E + 255) / 256, 256, 0, stream>>>(node_gid, bond_gid, cnt_node, cnt_bond, N, E);
  factor_kernel<<<(G + 255) / 256, 256, 0, stream>>>(cnt_node, cnt_bond, fac_node, fac_bond,
                                                     recip_node, G);

  // ---- CSR for bond-angle graph ----
  deg_kernel<<<(A + 255) / 256, 256, 0, stream>>>(ba_dst, deg_e, A);
  int nbE = (E + 255) / 256;
  scan1_kernel<<<nbE, 256, 0, stream>>>(deg_e, off_e, bsum, E);
  scan2_kernel<<<1, 1024, 0, stream>>>(bsum, nbE);
  scan3_kernel<<<nbE, 256, 0, stream>>>(off_e, bsum, E);
  fill_kernel<<<(A + 255) / 256, 256, 0, stream>>>(ba_dst, off_e, cur_e, csr_e, A);

  angle_gather_kernel<<<(E + 3) / 4, 256, 0, stream>>>(bond_angle, ba_src, edge_hidden,
                                                       off_e, deg_e, csr_e, rbf_w, rbf_b,
                                                       out_edge, E);
  mlp_kernel<0><<<(E + 31) / 32, 256, 0, stream>>>(out_edge, out_edge, edge_hidden, bond_gid,
                                                   fac_bond, w1p_ba, ba_b1, w2p_ba, ba_b2,
                                                   ba_ln_g, ba_ln_b, nullptr, E);

  // ---- CSR for atom-bond graph ----
  deg_kernel<<<(E + 255) / 256, 256, 0, stream>>>(ab_dst, deg_n, E);
  int nbN = (N + 255) / 256;
  scan1_kernel<<<nbN, 256, 0, stream>>>(deg_n, off_n, bsum, N);
  scan2_kernel<<<1, 1024, 0, stream>>>(bsum, nbN);
  scan3_kernel<<<nbN, 256, 0, stream>>>(off_n, bsum, N);
  fill_kernel<<<(E + 255) / 256, 256, 0, stream>>>(ab_dst, off_n, cur_n, csr_n, E);

  node_gather_kernel<<<(N + 3) / 4, 256, 0, stream>>>(node_hidden, out_edge, ab_src,
                                                      off_n, deg_n, csr_n, out_node, N);
  mlp_kernel<1><<<(N + 31) / 32, 256, 0, stream>>>(out_node, out_node, node_hidden, node_gid,
                                                   fac_node, w1p_ab, ab_b1, w2p_ab, ab_b2,
                                                   ab_ln_g, ab_ln_b, out_graph, N);

  pooldiv_kernel<<<G, 256, 0, stream>>>(out_graph, recip_node);
}

// Round 7
// 660.556 us; speedup vs baseline: 1.7229x; 1.0966x over previous
//
#include <hip/hip_runtime.h>

#define HDIM 256
#define LNEPS 1e-5f

typedef float f32x4 __attribute__((ext_vector_type(4)));
typedef short bf16x8 __attribute__((ext_vector_type(8)));

static __device__ __forceinline__ unsigned short f2b(float f) {
  union { float f; unsigned u; } v; v.f = f;
  return (unsigned short)((v.u + 0x7fffu + ((v.u >> 16) & 1u)) >> 16);
}
static __device__ __forceinline__ unsigned pk2(float lo, float hi) {
  return (unsigned)f2b(lo) | ((unsigned)f2b(hi) << 16);
}

// ---------------- weight repack into 8KB fragment-ordered slabs ----------------
// Slab layout TRANSPOSED for conflict-free ds_read: element (lg, n1l, ke) at index
// (lg*128 + n1l)*8 + ke  -> fragment byte addr = lg*2048 + n1l*16. Consecutive l15
// lanes read consecutive 16B (canonical conflict-free). Old layout had n1l stride
// 64B -> 8-way bank conflict (the +1.26e7 SQ_LDS_BANK_CONFLICT delta of round 6).
// w1 [256 k][512 n1] -> slabs (h,kk): k = kk*32 + lg*8 + ke, n1 = h*128 + n1l.
__global__ void pack1_kernel(const float* __restrict__ in, unsigned short* __restrict__ out) {
  int o = blockIdx.x * 256 + threadIdx.x;  // 131072
  int ke = o & 7, n1l = (o >> 3) & 127, lg = (o >> 10) & 3, sl = o >> 12;
  int h = sl >> 3, kk = sl & 7;
  int k = kk * 32 + lg * 8 + ke, n1 = h * 128 + n1l;
  out[o] = f2b(in[k * 512 + n1]);
}

// w2 [512 k2][256 n2] -> slabs (h,h2,kk2): k2 = h*128 + kk2*32 + lg*8 + ke, n2 = h2*128 + n2l.
__global__ void pack2_kernel(const float* __restrict__ in, unsigned short* __restrict__ out) {
  int o = blockIdx.x * 256 + threadIdx.x;  // 131072
  int ke = o & 7, n2l = (o >> 3) & 127, lg = (o >> 10) & 3, sl = o >> 12;
  int h = sl >> 3, r = sl & 7, h2 = r >> 2, kk2 = r & 3;
  int k2 = h * 128 + kk2 * 32 + lg * 8 + ke, n2 = h2 * 128 + n2l;
  out[o] = f2b(in[k2 * 256 + n2]);
}

// ---------------- per-graph counts ----------------
__global__ void count_kernel(const int* __restrict__ node_gid, const int* __restrict__ bond_gid,
                             int* cnt_node, int* cnt_bond, int N, int E) {
  int i = blockIdx.x * 256 + threadIdx.x;
  if (i < N) atomicAdd(&cnt_node[node_gid[i]], 1);
  if (i < E) atomicAdd(&cnt_bond[bond_gid[i]], 1);
}

__global__ void factor_kernel(const int* __restrict__ cnt_node, const int* __restrict__ cnt_bond,
                              float* fac_node, float* fac_bond, float* recip_node, int G) {
  int g = blockIdx.x * 256 + threadIdx.x;
  if (g >= G) return;
  float cn = fmaxf((float)cnt_node[g], 1.f);
  float cb = fmaxf((float)cnt_bond[g], 1.f);
  fac_node[g] = rsqrtf(cn);
  fac_bond[g] = rsqrtf(cb);
  recip_node[g] = 1.f / cn;
}

// ---------------- CSR build ----------------
__global__ void deg_kernel(const int* __restrict__ dst, int* __restrict__ deg, int n) {
  int i = blockIdx.x * 256 + threadIdx.x;
  if (i < n) atomicAdd(&deg[dst[i]], 1);
}

__global__ void scan1_kernel(const int* __restrict__ deg, int* __restrict__ excl,
                             int* __restrict__ bsum, int n) {
  int t = threadIdx.x;
  int i = blockIdx.x * 256 + t;
  int v = (i < n) ? deg[i] : 0;
  int lane = t & 63, w = t >> 6;
  int s = v;
#pragma unroll
  for (int d = 1; d < 64; d <<= 1) {
    int u = __shfl_up(s, d);
    if (lane >= d) s += u;
  }
  __shared__ int wsum[4];
  if (lane == 63) wsum[w] = s;
  __syncthreads();
  int base = 0;
  for (int ww = 0; ww < w; ++ww) base += wsum[ww];
  if (i < n) excl[i] = base + s - v;
  if (t == 255) bsum[blockIdx.x] = base + s;
}

__global__ void scan2_kernel(int* __restrict__ bsum, int nb) {
  int t = threadIdx.x;  // 1024 threads
  int v = (t < nb) ? bsum[t] : 0;
  int lane = t & 63, w = t >> 6;
  int s = v;
#pragma unroll
  for (int d = 1; d < 64; d <<= 1) {
    int u = __shfl_up(s, d);
    if (lane >= d) s += u;
  }
  __shared__ int wsum[16];
  if (lane == 63) wsum[w] = s;
  __syncthreads();
  int base = 0;
  for (int ww = 0; ww < w; ++ww) base += wsum[ww];
  if (t < nb) bsum[t] = base + s - v;
}

__global__ void scan3_kernel(int* __restrict__ excl, const int* __restrict__ bsum, int n) {
  int i = blockIdx.x * 256 + threadIdx.x;
  if (i < n) excl[i] += bsum[blockIdx.x];
}

__global__ void fill_kernel(const int* __restrict__ dst, const int* __restrict__ off,
                            int* __restrict__ cursor, int* __restrict__ csr, int n) {
  int i = blockIdx.x * 256 + threadIdx.x;
  if (i >= n) return;
  int d = dst[i];
  int p = atomicAdd(&cursor[d], 1);
  csr[off[d] + p] = i;
}

// ---------------- gather: agg_e[d] = (Σ rbf_a)@W + cnt·b + Σ edge_hidden[src_a] ----------------
__global__ __launch_bounds__(256) void angle_gather_kernel(
    const float* __restrict__ bond_angle, const int* __restrict__ ba_src,
    const float* __restrict__ edge_hidden,
    const int* __restrict__ off, const int* __restrict__ deg, const int* __restrict__ csr,
    const float* __restrict__ rbf_w, const float* __restrict__ rbf_b,
    float* __restrict__ agg_e, int E) {
  int w = threadIdx.x >> 6, lane = threadIdx.x & 63;
  int d = blockIdx.x * 4 + w;
  if (d >= E) return;
  int c4 = lane * 4;
  int start = off[d], cnt = deg[d];
  f32x4 acc = (f32x4)0.f;
  float rbfs = 0.f;
  float cc = 0.1f * (float)(lane & 31);
  for (int i = 0; i < cnt; ++i) {
    int a = csr[start + i];
    float av = bond_angle[a];
    if (lane < 32) {
      float dd = av - cc;
      rbfs += __expf(-10.f * dd * dd);
    }
    int s = ba_src[a];
    acc += *(const f32x4*)&edge_hidden[(size_t)s * HDIM + c4];
  }
#pragma unroll
  for (int k = 0; k < 32; ++k) {
    float rv = __shfl(rbfs, k);
    f32x4 wv = *(const f32x4*)&rbf_w[k * HDIM + c4];
    acc[0] += rv * wv[0]; acc[1] += rv * wv[1];
    acc[2] += rv * wv[2]; acc[3] += rv * wv[3];
  }
  f32x4 bv = *(const f32x4*)&rbf_b[c4];
  float fc = (float)cnt;
  acc[0] += fc * bv[0]; acc[1] += fc * bv[1];
  acc[2] += fc * bv[2]; acc[3] += fc * bv[3];
  *(f32x4*)&agg_e[(size_t)d * HDIM + c4] = acc;
}

// ---------------- gather: agg_n[d] = Σ (edge_out[e] + node_hidden[src_e]) ----------------
__global__ __launch_bounds__(256) void node_gather_kernel(
    const float* __restrict__ node_hidden, const float* __restrict__ edge_out,
    const int* __restrict__ ab_src,
    const int* __restrict__ off, const int* __restrict__ deg, const int* __restrict__ csr,
    float* __restrict__ agg_n, int N) {
  int w = threadIdx.x >> 6, lane = threadIdx.x & 63;
  int d = blockIdx.x * 4 + w;
  if (d >= N) return;
  int c4 = lane * 4;
  int start = off[d], cnt = deg[d];
  f32x4 acc = (f32x4)0.f;
  for (int i = 0; i < cnt; ++i) {
    int e = csr[start + i];
    int s = ab_src[e];
    f32x4 a = *(const f32x4*)&edge_out[(size_t)e * HDIM + c4];
    f32x4 b = *(const f32x4*)&node_hidden[(size_t)s * HDIM + c4];
    acc += a;
    acc += b;
  }
  *(f32x4*)&agg_n[(size_t)d * HDIM + c4] = acc;
}

// ---------------- fused MLP + LayerNorm + graph_normal + residual (+pool) ----------------
// 32 rows/block, 256 threads (4 waves), LDS 40960B -> 4 blocks/CU.
// 64 slab-steps, double-buffered with DISTANCE-2 prefetch: loads for slab s+2 issued
// at step s, ds_written at step s+1, read at step s+2 -> one full step (~500cyc) of
// compute covers the L2 latency (round-6's distance-1 stalled ~300cyc/step at the
// vmcnt before ds_write). Slabs are transposed [lg][n1l] -> conflict-free ds_read.
template <int POOL>
__global__ __launch_bounds__(256, 4) void mlp_kernel(
    const float* agg_in, float* out_rows,  // may alias (in-place per-block)
    const float* __restrict__ residual, const int* __restrict__ gid,
    const float* __restrict__ gfactor,
    const unsigned short* __restrict__ w1p, const float* __restrict__ b1,
    const unsigned short* __restrict__ w2p, const float* __restrict__ b2,
    const float* __restrict__ ln_g, const float* __restrict__ ln_b,
    float* pool_out, int M) {
  __shared__ __align__(16) char smem[40960];
  char* Xb = smem;                         // bf16 [32][256] swizzled, 16KB
  char* Hb = smem + 16384;                 // bf16 [32][128] quarter, swizzled, 8KB
  char* Wb = smem + 24576;                 // 2 x 8KB weight-slab double buffer
  float* Outs = (float*)smem;              // f32 [32][256], overlays Xb+Hb+Wb[0] post-GEMM
  float* fstat = (float*)(smem + 40448);   // [32][2] mean/rstd (in dead Wb[1] tail)
  float* gfs = (float*)(smem + 40704);     // [32]
  int* gid_s = (int*)(smem + 40832);       // [32]

  int t = threadIdx.x;
  int row0 = blockIdx.x * 32;
  int w = t >> 6, lane = t & 63;
  int l15 = lane & 15, lg = lane >> 4;

  auto slab_ptr = [&](int ss) -> const uint4* {
    int hh = ss >> 4, r = ss & 15;
    const unsigned short* p = (r < 8) ? (w1p + (size_t)(hh * 8 + r) * 4096)
                                      : (w2p + (size_t)(hh * 8 + (r - 8)) * 4096);
    return (const uint4*)p;
  };

  uint4 rA0, rA1, rB0, rB1;  // in-flight slab registers (named, never runtime-indexed)

  // ---- prologue: slab0 -> Wb[0]; slab1 -> regs; stage X (f32 -> bf16 swizzled) ----
  {
    const uint4* g0 = slab_ptr(0);
    uint4 s0a = g0[t], s0b = g0[t + 256];
    const uint4* g1 = slab_ptr(1);
    rA0 = g1[t]; rA1 = g1[t + 256];
    int row = t >> 3;
    int c0 = (t & 7) * 32;
    int gr = row0 + row; if (gr >= M) gr = M - 1;
    const float* src = agg_in + (size_t)gr * HDIM + c0;
#pragma unroll
    for (int i = 0; i < 4; ++i) {
      f32x4 a = *(const f32x4*)(src + i * 8);
      f32x4 b = *(const f32x4*)(src + i * 8 + 4);
      int byte = (row * 512 + (c0 + i * 8) * 2) ^ ((row & 7) << 4);
      *(uint4*)(Xb + byte) =
          make_uint4(pk2(a[0], a[1]), pk2(a[2], a[3]), pk2(b[0], b[1]), pk2(b[2], b[3]));
    }
    *(uint4*)(Wb + t * 16) = s0a;
    *(uint4*)(Wb + (t + 256) * 16) = s0b;
  }
  __syncthreads();

  f32x4 acc2[2][4];  // [mt][h2*2+nf] : row = mt*16+lg*4+jr ; col = h2*128+w*32+nf*16+l15
#pragma unroll
  for (int mt = 0; mt < 2; ++mt)
#pragma unroll
    for (int nf = 0; nf < 4; ++nf) acc2[mt][nf] = (f32x4)0.f;

  int s = 0;
  for (int h = 0; h < 4; ++h) {
    f32x4 acc1[2][2];  // [tt][mt]
#pragma unroll
    for (int tt = 0; tt < 2; ++tt)
#pragma unroll
      for (int mt = 0; mt < 2; ++mt) acc1[tt][mt] = (f32x4)0.f;

    // ---- GEMM1 quarter: n1 = h*128 + w*32 + tt*16 + l15, k = kk*32 + lg*8 ----
    for (int kk = 0; kk < 8; ++kk) {
      if (s + 2 < 64) { const uint4* g = slab_ptr(s + 2); rB0 = g[t]; rB1 = g[t + 256]; }
      const char* buf = Wb + (s & 1) * 8192;
      bf16x8 xfr[2], afr[2];
#pragma unroll
      for (int mt = 0; mt < 2; ++mt) {
        int m = mt * 16 + l15;
        int byte = (m * 512 + kk * 64 + lg * 16) ^ ((m & 7) << 4);
        xfr[mt] = *(const bf16x8*)(Xb + byte);
      }
#pragma unroll
      for (int tt = 0; tt < 2; ++tt)
        afr[tt] = *(const bf16x8*)(buf + lg * 2048 + (w * 32 + tt * 16 + l15) * 16);
#pragma unroll
      for (int tt = 0; tt < 2; ++tt)
#pragma unroll
        for (int mt = 0; mt < 2; ++mt)
          acc1[tt][mt] = __builtin_amdgcn_mfma_f32_16x16x32_bf16(afr[tt], xfr[mt], acc1[tt][mt], 0, 0, 0);

      if (kk == 7) {
        // bias + relu + packed Hb store: Hb[m][n1l], n1l = w*32 + tt*16 + lg*4 (+0..3)
#pragma unroll
        for (int tt = 0; tt < 2; ++tt) {
          f32x4 b1v = *(const f32x4*)&b1[h * 128 + w * 32 + tt * 16 + lg * 4];
#pragma unroll
          for (int mt = 0; mt < 2; ++mt) {
            f32x4 v = acc1[tt][mt] + b1v;
            v[0] = fmaxf(v[0], 0.f); v[1] = fmaxf(v[1], 0.f);
            v[2] = fmaxf(v[2], 0.f); v[3] = fmaxf(v[3], 0.f);
            int m = mt * 16 + l15;
            int n1l = w * 32 + tt * 16 + lg * 4;
            int byte = (m * 256 + n1l * 2) ^ ((m & 7) << 4);
            *(uint2*)(Hb + byte) = make_uint2(pk2(v[0], v[1]), pk2(v[2], v[3]));
          }
        }
      }
      if (s + 1 < 64) {
        char* nb = Wb + ((s + 1) & 1) * 8192;
        *(uint4*)(nb + t * 16) = rA0;
        *(uint4*)(nb + (t + 256) * 16) = rA1;
      }
      __syncthreads();
      rA0 = rB0; rA1 = rB1;
      ++s;
    }

    // ---- GEMM2 partial: n2 = h2*128 + w*32 + nf*16 + l15, k2-local = kk2*32 + lg*8 ----
#pragma unroll
    for (int h2 = 0; h2 < 2; ++h2) {
#pragma unroll
      for (int kk2 = 0; kk2 < 4; ++kk2) {
        if (s + 2 < 64) { const uint4* g = slab_ptr(s + 2); rB0 = g[t]; rB1 = g[t + 256]; }
        const char* buf = Wb + (s & 1) * 8192;
        bf16x8 hfr[2], wfr[2];
#pragma unroll
        for (int mt = 0; mt < 2; ++mt) {
          int m = mt * 16 + l15;
          int byte = (m * 256 + kk2 * 64 + lg * 16) ^ ((m & 7) << 4);
          hfr[mt] = *(const bf16x8*)(Hb + byte);
        }
#pragma unroll
        for (int nf = 0; nf < 2; ++nf)
          wfr[nf] = *(const bf16x8*)(buf + lg * 2048 + (w * 32 + nf * 16 + l15) * 16);
#pragma unroll
        for (int mt = 0; mt < 2; ++mt)
#pragma unroll
          for (int nf = 0; nf < 2; ++nf)
            acc2[mt][h2 * 2 + nf] =
                __builtin_amdgcn_mfma_f32_16x16x32_bf16(hfr[mt], wfr[nf], acc2[mt][h2 * 2 + nf], 0, 0, 0);
        if (s + 1 < 64) {
          char* nb = Wb + ((s + 1) & 1) * 8192;
          *(uint4*)(nb + t * 16) = rA0;
          *(uint4*)(nb + (t + 256) * 16) = rA1;
        }
        __syncthreads();
        rA0 = rB0; rA1 = rB1;
        ++s;
      }
    }
  }

  // ---- Outs = acc2 + b2 (f32 LDS); graph factors (post-GEMM: stats region now dead) ----
#pragma unroll
  for (int nf = 0; nf < 4; ++nf) {
    int col = (nf >> 1) * 128 + w * 32 + (nf & 1) * 16 + l15;
    float b2v = b2[col];
#pragma unroll
    for (int mt = 0; mt < 2; ++mt)
#pragma unroll
      for (int jr = 0; jr < 4; ++jr)
        Outs[(mt * 16 + lg * 4 + jr) * 256 + col] = acc2[mt][nf][jr] + b2v;
  }
  if (t < 32) {
    int r = row0 + t;
    int g = (r < M) ? gid[r] : 0;
    gid_s[t] = g;
    gfs[t] = gfactor[g];
  }
  __syncthreads();

  // ---- LayerNorm stats: 8 threads per row ----
  {
    int row = t >> 3, sub = t & 7;
    float ssum = 0.f, ss = 0.f;
#pragma unroll
    for (int i = 0; i < 8; ++i) {
      f32x4 v = *(const f32x4*)&Outs[row * 256 + sub * 32 + i * 4];
      ssum += v[0] + v[1] + v[2] + v[3];
      ss += v[0] * v[0] + v[1] * v[1] + v[2] * v[2] + v[3] * v[3];
    }
    ssum += __shfl_xor(ssum, 1); ss += __shfl_xor(ss, 1);
    ssum += __shfl_xor(ssum, 2); ss += __shfl_xor(ss, 2);
    ssum += __shfl_xor(ssum, 4); ss += __shfl_xor(ss, 4);
    if (sub == 0) {
      float mean = ssum * (1.f / 256.f);
      float var = ss * (1.f / 256.f) - mean * mean;
      fstat[row * 2] = mean;
      fstat[row * 2 + 1] = rsqrtf(var + LNEPS);
    }
  }
  __syncthreads();

  // ---- finalize: LN affine, graph_normal, residual, store (+segmented pool) ----
  {
    float g_t = ln_g[t], bb_t = ln_b[t];
    float psum = 0.f;
    int curg = -1;
#pragma unroll 4
    for (int p = 0; p < 32; ++p) {
      int gr = row0 + p;
      if (gr < M) {
        float v = Outs[p * 256 + t];
        v = (v - fstat[p * 2]) * fstat[p * 2 + 1] * g_t + bb_t;
        v *= gfs[p];
        v += residual[(size_t)gr * HDIM + t];
        out_rows[(size_t)gr * HDIM + t] = v;
        if (POOL) {
          int g = gid_s[p];
          if (g != curg) {
            if (curg >= 0) atomicAdd(&pool_out[(size_t)curg * HDIM + t], psum);
            psum = 0.f;
            curg = g;
          }
          psum += v;
        }
      }
    }
    if (POOL && curg >= 0) atomicAdd(&pool_out[(size_t)curg * HDIM + t], psum);
  }
}

// ---------------- pooled sums -> means ----------------
__global__ void pooldiv_kernel(float* out_graph, const float* __restrict__ recip_node) {
  int g = blockIdx.x, t = threadIdx.x;
  out_graph[(size_t)g * HDIM + t] *= recip_node[g];
}

extern "C" void kernel_launch(void* const* d_in, const int* in_sizes, int n_in,
                              void* d_out, int out_size, void* d_ws, size_t ws_size,
                              hipStream_t stream) {
  const float* node_hidden = (const float*)d_in[0];
  const float* edge_hidden = (const float*)d_in[1];
  const float* bond_angle = (const float*)d_in[2];
  const int* ab_src = (const int*)d_in[3];
  const int* ab_dst = (const int*)d_in[4];
  const int* ba_src = (const int*)d_in[5];
  const int* ba_dst = (const int*)d_in[6];
  const int* node_gid = (const int*)d_in[7];
  const int* bond_gid = (const int*)d_in[8];
  const float* rbf_w = (const float*)d_in[10];
  const float* rbf_b = (const float*)d_in[11];
  const float* ba_w1 = (const float*)d_in[12];
  const float* ba_b1 = (const float*)d_in[13];
  const float* ba_w2 = (const float*)d_in[14];
  const float* ba_b2 = (const float*)d_in[15];
  const float* ba_ln_g = (const float*)d_in[16];
  const float* ba_ln_b = (const float*)d_in[17];
  const float* ab_w1 = (const float*)d_in[18];
  const float* ab_b1 = (const float*)d_in[19];
  const float* ab_w2 = (const float*)d_in[20];
  const float* ab_b2 = (const float*)d_in[21];
  const float* ab_ln_g = (const float*)d_in[22];
  const float* ab_ln_b = (const float*)d_in[23];

  int N = in_sizes[0] / HDIM;
  int E = in_sizes[1] / HDIM;
  int A = in_sizes[2];
  int G = out_size / HDIM - N - E;

  float* out_node = (float*)d_out;
  float* out_edge = out_node + (size_t)N * HDIM;
  float* out_graph = out_edge + (size_t)E * HDIM;

  // ---- workspace layout ----
  char* ws = (char*)d_ws;
  int* cnt_node = (int*)ws;                    // G   (zeroed)
  int* cnt_bond = cnt_node + G;                // G   (zeroed)
  int* deg_e = cnt_bond + G;                   // E   (zeroed)
  int* cur_e = deg_e + E;                      // E   (zeroed)
  int* deg_n = cur_e + E;                      // N   (zeroed)
  int* cur_n = deg_n + N;                      // N   (zeroed)
  size_t zero_bytes = (size_t)(2 * G + 2 * E + 2 * N) * 4;
  float* fac_node = (float*)(cur_n + N);       // G
  float* fac_bond = fac_node + G;              // G
  float* recip_node = fac_bond + G;            // G
  int* off_e = (int*)(recip_node + G);         // E
  int* csr_e = off_e + E;                      // A
  int* off_n = csr_e + A;                      // N
  int* csr_n = off_n + N;                      // E
  int* bsum = csr_n + E;                       // 1024
  size_t off = ((size_t)((char*)(bsum + 1024) - ws) + 255) & ~(size_t)255;
  unsigned short* w1p_ba = (unsigned short*)(ws + off); off += (size_t)512 * 256 * 2;
  unsigned short* w2p_ba = (unsigned short*)(ws + off); off += (size_t)256 * 512 * 2;
  unsigned short* w1p_ab = (unsigned short*)(ws + off); off += (size_t)512 * 256 * 2;
  unsigned short* w2p_ab = (unsigned short*)(ws + off); off += (size_t)256 * 512 * 2;

  hipMemsetAsync(d_ws, 0, zero_bytes, stream);
  hipMemsetAsync(out_graph, 0, (size_t)G * HDIM * 4, stream);

  pack1_kernel<<<512, 256, 0, stream>>>(ba_w1, w1p_ba);
  pack2_kernel<<<512, 256, 0, stream>>>(ba_w2, w2p_ba);
  pack1_kernel<<<512, 256, 0, stream>>>(ab_w1, w1p_ab);
  pack2_kernel<<<512, 256, 0, stream>>>(ab_w2, w2p_ab);

  count_kernel<<<(E + 255) / 256, 256, 0, stream>>>(node_gid, bond_gid, cnt_node, cnt_bond, N, E);
  factor_kernel<<<(G + 255) / 256, 256, 0, stream>>>(cnt_node, cnt_bond, fac_node, fac_bond,
                                                     recip_node, G);

  // ---- CSR for bond-angle graph ----
  deg_kernel<<<(A + 255) / 256, 256, 0, stream>>>(ba_dst, deg_e, A);
  int nbE = (E + 255) / 256;
  scan1_kernel<<<nbE, 256, 0, stream>>>(deg_e, off_e, bsum, E);
  scan2_kernel<<<1, 1024, 0, stream>>>(bsum, nbE);
  scan3_kernel<<<nbE, 256, 0, stream>>>(off_e, bsum, E);
  fill_kernel<<<(A + 255) / 256, 256, 0, stream>>>(ba_dst, off_e, cur_e, csr_e, A);

  angle_gather_kernel<<<(E + 3) / 4, 256, 0, stream>>>(bond_angle, ba_src, edge_hidden,
                                                       off_e, deg_e, csr_e, rbf_w, rbf_b,
                                                       out_edge, E);
  mlp_kernel<0><<<(E + 31) / 32, 256, 0, stream>>>(out_edge, out_edge, edge_hidden, bond_gid,
                                                   fac_bond, w1p_ba, ba_b1, w2p_ba, ba_b2,
                                                   ba_ln_g, ba_ln_b, nullptr, E);

  // ---- CSR for atom-bond graph ----
  deg_kernel<<<(E + 255) / 256, 256, 0, stream>>>(ab_dst, deg_n, E);
  int nbN = (N + 255) / 256;
  scan1_kernel<<<nbN, 256, 0, stream>>>(deg_n, off_n, bsum, N);
  scan2_kernel<<<1, 1024, 0, stream>>>(bsum, nbN);
  scan3_kernel<<<nbN, 256, 0, stream>>>(off_n, bsum, N);
  fill_kernel<<<(E + 255) / 256, 256, 0, stream>>>(ab_dst, off_n, cur_n, csr_n, E);

  node_gather_kernel<<<(N + 3) / 4, 256, 0, stream>>>(node_hidden, out_edge, ab_src,
                                                      off_n, deg_n, csr_n, out_node, N);
  mlp_kernel<1><<<(N + 31) / 32, 256, 0, stream>>>(out_node, out_node, node_hidden, node_gid,
                                                   fac_node, w1p_ab, ab_b1, w2p_ab, ab_b2,
                                                   ab_ln_g, ab_ln_b, out_graph, N);

  pooldiv_kernel<<<G, 256, 0, stream>>>(out_graph, recip_node);
}

// Round 8
// 647.662 us; speedup vs baseline: 1.7572x; 1.0199x over previous
//
#include <hip/hip_runtime.h>

#define HDIM 256
#define LNEPS 1e-5f

typedef float f32x4 __attribute__((ext_vector_type(4)));
typedef short bf16x8 __attribute__((ext_vector_type(8)));

static __device__ __forceinline__ unsigned short f2b(float f) {
  union { float f; unsigned u; } v; v.f = f;
  return (unsigned short)((v.u + 0x7fffu + ((v.u >> 16) & 1u)) >> 16);
}
static __device__ __forceinline__ unsigned pk2(float lo, float hi) {
  return (unsigned)f2b(lo) | ((unsigned)f2b(hi) << 16);
}

// ---------------- weight repack into 8KB fragment-ordered slabs ----------------
// Transposed [lg][n1l] layout: fragment byte = lg*2048 + n1l*16 (conflict-free ds_read).
__global__ void pack1_kernel(const float* __restrict__ in, unsigned short* __restrict__ out) {
  int o = blockIdx.x * 256 + threadIdx.x;  // 131072
  int ke = o & 7, n1l = (o >> 3) & 127, lg = (o >> 10) & 3, sl = o >> 12;
  int h = sl >> 3, kk = sl & 7;
  int k = kk * 32 + lg * 8 + ke, n1 = h * 128 + n1l;
  out[o] = f2b(in[k * 512 + n1]);
}

__global__ void pack2_kernel(const float* __restrict__ in, unsigned short* __restrict__ out) {
  int o = blockIdx.x * 256 + threadIdx.x;  // 131072
  int ke = o & 7, n2l = (o >> 3) & 127, lg = (o >> 10) & 3, sl = o >> 12;
  int h = sl >> 3, r = sl & 7, h2 = r >> 2, kk2 = r & 3;
  int k2 = h * 128 + kk2 * 32 + lg * 8 + ke, n2 = h2 * 128 + n2l;
  out[o] = f2b(in[k2 * 256 + n2]);
}

// ---------------- per-graph counts ----------------
__global__ void count_kernel(const int* __restrict__ node_gid, const int* __restrict__ bond_gid,
                             int* cnt_node, int* cnt_bond, int N, int E) {
  int i = blockIdx.x * 256 + threadIdx.x;
  if (i < N) atomicAdd(&cnt_node[node_gid[i]], 1);
  if (i < E) atomicAdd(&cnt_bond[bond_gid[i]], 1);
}

__global__ void factor_kernel(const int* __restrict__ cnt_node, const int* __restrict__ cnt_bond,
                              float* fac_node, float* fac_bond, float* recip_node, int G) {
  int g = blockIdx.x * 256 + threadIdx.x;
  if (g >= G) return;
  float cn = fmaxf((float)cnt_node[g], 1.f);
  float cb = fmaxf((float)cnt_bond[g], 1.f);
  fac_node[g] = rsqrtf(cn);
  fac_bond[g] = rsqrtf(cb);
  recip_node[g] = 1.f / cn;
}

// ---------------- CSR build ----------------
__global__ void deg_kernel(const int* __restrict__ dst, int* __restrict__ deg, int n) {
  int i = blockIdx.x * 256 + threadIdx.x;
  if (i < n) atomicAdd(&deg[dst[i]], 1);
}

__global__ void scan1_kernel(const int* __restrict__ deg, int* __restrict__ excl,
                             int* __restrict__ bsum, int n) {
  int t = threadIdx.x;
  int i = blockIdx.x * 256 + t;
  int v = (i < n) ? deg[i] : 0;
  int lane = t & 63, w = t >> 6;
  int s = v;
#pragma unroll
  for (int d = 1; d < 64; d <<= 1) {
    int u = __shfl_up(s, d);
    if (lane >= d) s += u;
  }
  __shared__ int wsum[4];
  if (lane == 63) wsum[w] = s;
  __syncthreads();
  int base = 0;
  for (int ww = 0; ww < w; ++ww) base += wsum[ww];
  if (i < n) excl[i] = base + s - v;
  if (t == 255) bsum[blockIdx.x] = base + s;
}

__global__ void scan2_kernel(int* __restrict__ bsum, int nb) {
  int t = threadIdx.x;  // 1024 threads
  int v = (t < nb) ? bsum[t] : 0;
  int lane = t & 63, w = t >> 6;
  int s = v;
#pragma unroll
  for (int d = 1; d < 64; d <<= 1) {
    int u = __shfl_up(s, d);
    if (lane >= d) s += u;
  }
  __shared__ int wsum[16];
  if (lane == 63) wsum[w] = s;
  __syncthreads();
  int base = 0;
  for (int ww = 0; ww < w; ++ww) base += wsum[ww];
  if (t < nb) bsum[t] = base + s - v;
}

__global__ void scan3_kernel(int* __restrict__ excl, const int* __restrict__ bsum, int n) {
  int i = blockIdx.x * 256 + threadIdx.x;
  if (i < n) excl[i] += bsum[blockIdx.x];
}

__global__ void fill_kernel(const int* __restrict__ dst, const int* __restrict__ off,
                            int* __restrict__ cursor, int* __restrict__ csr, int n) {
  int i = blockIdx.x * 256 + threadIdx.x;
  if (i >= n) return;
  int d = dst[i];
  int p = atomicAdd(&cursor[d], 1);
  csr[off[d] + p] = i;
}

// ---------------- gather: agg_e[d] = (Σ rbf_a)@W + cnt·b + Σ edge_hidden[src_a] ----------
// LANE-PARALLEL INDEX CHASE (fix for round-7's ~1040 cyc/wave serial chain): all edge
// indices of a row fetched in ONE lane-parallel load, ba_src/bond_angle likewise
// (chain depth 3 total instead of cnt*2); row loads then have known addresses and
// unroll-4 puts 4x 1KB reads in flight per wave.
__global__ __launch_bounds__(256) void angle_gather_kernel(
    const float* __restrict__ bond_angle, const int* __restrict__ ba_src,
    const float* __restrict__ edge_hidden,
    const int* __restrict__ off, const int* __restrict__ deg, const int* __restrict__ csr,
    const float* __restrict__ rbf_w, const float* __restrict__ rbf_b,
    float* __restrict__ agg_e, int E) {
  int w = threadIdx.x >> 6, lane = threadIdx.x & 63;
  int d = blockIdx.x * 4 + w;
  if (d >= E) return;
  int c4 = lane * 4;
  int start = off[d], cnt = deg[d];
  f32x4 acc = (f32x4)0.f;
  float rbfs = 0.f;
  float cc = 0.1f * (float)(lane & 31);
  for (int base = 0; base < cnt; base += 64) {
    int n = cnt - base; if (n > 64) n = 64;
    float av = 0.f;
    int s = 0;
    if (lane < n) {
      int a = csr[start + base + lane];
      av = bond_angle[a];
      s = ba_src[a];
    }
#pragma unroll 4
    for (int i = 0; i < n; ++i) {
      float avi = __shfl(av, i);
      int si = __shfl(s, i);
      if (lane < 32) {
        float dd = avi - cc;
        rbfs += __expf(-10.f * dd * dd);
      }
      acc += *(const f32x4*)&edge_hidden[(size_t)si * HDIM + c4];
    }
  }
#pragma unroll
  for (int k = 0; k < 32; ++k) {
    float rv = __shfl(rbfs, k);
    f32x4 wv = *(const f32x4*)&rbf_w[k * HDIM + c4];
    acc[0] += rv * wv[0]; acc[1] += rv * wv[1];
    acc[2] += rv * wv[2]; acc[3] += rv * wv[3];
  }
  f32x4 bv = *(const f32x4*)&rbf_b[c4];
  float fc = (float)cnt;
  acc[0] += fc * bv[0]; acc[1] += fc * bv[1];
  acc[2] += fc * bv[2]; acc[3] += fc * bv[3];
  *(f32x4*)&agg_e[(size_t)d * HDIM + c4] = acc;
}

// ---------------- gather: agg_n[d] = Σ (edge_out[e] + node_hidden[src_e]) --------------
// Same lane-parallel index chase.
__global__ __launch_bounds__(256) void node_gather_kernel(
    const float* __restrict__ node_hidden, const float* __restrict__ edge_out,
    const int* __restrict__ ab_src,
    const int* __restrict__ off, const int* __restrict__ deg, const int* __restrict__ csr,
    float* __restrict__ agg_n, int N) {
  int w = threadIdx.x >> 6, lane = threadIdx.x & 63;
  int d = blockIdx.x * 4 + w;
  if (d >= N) return;
  int c4 = lane * 4;
  int start = off[d], cnt = deg[d];
  f32x4 acc = (f32x4)0.f;
  for (int base = 0; base < cnt; base += 64) {
    int n = cnt - base; if (n > 64) n = 64;
    int e = 0, s = 0;
    if (lane < n) {
      e = csr[start + base + lane];
      s = ab_src[e];
    }
#pragma unroll 4
    for (int i = 0; i < n; ++i) {
      int ei = __shfl(e, i);
      int si = __shfl(s, i);
      f32x4 a = *(const f32x4*)&edge_out[(size_t)ei * HDIM + c4];
      f32x4 b = *(const f32x4*)&node_hidden[(size_t)si * HDIM + c4];
      acc += a;
      acc += b;
    }
  }
  *(f32x4*)&agg_n[(size_t)d * HDIM + c4] = acc;
}

// ---------------- fused MLP + LayerNorm + graph_normal + residual (+pool) ----------------
// (frozen from round 7: 64 slab-steps, distance-2 prefetch, transposed slabs)
template <int POOL>
__global__ __launch_bounds__(256, 4) void mlp_kernel(
    const float* agg_in, float* out_rows,  // may alias (in-place per-block)
    const float* __restrict__ residual, const int* __restrict__ gid,
    const float* __restrict__ gfactor,
    const unsigned short* __restrict__ w1p, const float* __restrict__ b1,
    const unsigned short* __restrict__ w2p, const float* __restrict__ b2,
    const float* __restrict__ ln_g, const float* __restrict__ ln_b,
    float* pool_out, int M) {
  __shared__ __align__(16) char smem[40960];
  char* Xb = smem;                         // bf16 [32][256] swizzled, 16KB
  char* Hb = smem + 16384;                 // bf16 [32][128] quarter, swizzled, 8KB
  char* Wb = smem + 24576;                 // 2 x 8KB weight-slab double buffer
  float* Outs = (float*)smem;              // f32 [32][256], overlays Xb+Hb+Wb[0] post-GEMM
  float* fstat = (float*)(smem + 40448);   // [32][2] mean/rstd (in dead Wb[1] tail)
  float* gfs = (float*)(smem + 40704);     // [32]
  int* gid_s = (int*)(smem + 40832);       // [32]

  int t = threadIdx.x;
  int row0 = blockIdx.x * 32;
  int w = t >> 6, lane = t & 63;
  int l15 = lane & 15, lg = lane >> 4;

  auto slab_ptr = [&](int ss) -> const uint4* {
    int hh = ss >> 4, r = ss & 15;
    const unsigned short* p = (r < 8) ? (w1p + (size_t)(hh * 8 + r) * 4096)
                                      : (w2p + (size_t)(hh * 8 + (r - 8)) * 4096);
    return (const uint4*)p;
  };

  uint4 rA0, rA1, rB0, rB1;  // in-flight slab registers (named, never runtime-indexed)

  // ---- prologue: slab0 -> Wb[0]; slab1 -> regs; stage X (f32 -> bf16 swizzled) ----
  {
    const uint4* g0 = slab_ptr(0);
    uint4 s0a = g0[t], s0b = g0[t + 256];
    const uint4* g1 = slab_ptr(1);
    rA0 = g1[t]; rA1 = g1[t + 256];
    int row = t >> 3;
    int c0 = (t & 7) * 32;
    int gr = row0 + row; if (gr >= M) gr = M - 1;
    const float* src = agg_in + (size_t)gr * HDIM + c0;
#pragma unroll
    for (int i = 0; i < 4; ++i) {
      f32x4 a = *(const f32x4*)(src + i * 8);
      f32x4 b = *(const f32x4*)(src + i * 8 + 4);
      int byte = (row * 512 + (c0 + i * 8) * 2) ^ ((row & 7) << 4);
      *(uint4*)(Xb + byte) =
          make_uint4(pk2(a[0], a[1]), pk2(a[2], a[3]), pk2(b[0], b[1]), pk2(b[2], b[3]));
    }
    *(uint4*)(Wb + t * 16) = s0a;
    *(uint4*)(Wb + (t + 256) * 16) = s0b;
  }
  __syncthreads();

  f32x4 acc2[2][4];  // [mt][h2*2+nf] : row = mt*16+lg*4+jr ; col = h2*128+w*32+nf*16+l15
#pragma unroll
  for (int mt = 0; mt < 2; ++mt)
#pragma unroll
    for (int nf = 0; nf < 4; ++nf) acc2[mt][nf] = (f32x4)0.f;

  int s = 0;
  for (int h = 0; h < 4; ++h) {
    f32x4 acc1[2][2];  // [tt][mt]
#pragma unroll
    for (int tt = 0; tt < 2; ++tt)
#pragma unroll
      for (int mt = 0; mt < 2; ++mt) acc1[tt][mt] = (f32x4)0.f;

    // ---- GEMM1 quarter: n1 = h*128 + w*32 + tt*16 + l15, k = kk*32 + lg*8 ----
    for (int kk = 0; kk < 8; ++kk) {
      if (s + 2 < 64) { const uint4* g = slab_ptr(s + 2); rB0 = g[t]; rB1 = g[t + 256]; }
      const char* buf = Wb + (s & 1) * 8192;
      bf16x8 xfr[2], afr[2];
#pragma unroll
      for (int mt = 0; mt < 2; ++mt) {
        int m = mt * 16 + l15;
        int byte = (m * 512 + kk * 64 + lg * 16) ^ ((m & 7) << 4);
        xfr[mt] = *(const bf16x8*)(Xb + byte);
      }
#pragma unroll
      for (int tt = 0; tt < 2; ++tt)
        afr[tt] = *(const bf16x8*)(buf + lg * 2048 + (w * 32 + tt * 16 + l15) * 16);
#pragma unroll
      for (int tt = 0; tt < 2; ++tt)
#pragma unroll
        for (int mt = 0; mt < 2; ++mt)
          acc1[tt][mt] = __builtin_amdgcn_mfma_f32_16x16x32_bf16(afr[tt], xfr[mt], acc1[tt][mt], 0, 0, 0);

      if (kk == 7) {
        // bias + relu + packed Hb store: Hb[m][n1l], n1l = w*32 + tt*16 + lg*4 (+0..3)
#pragma unroll
        for (int tt = 0; tt < 2; ++tt) {
          f32x4 b1v = *(const f32x4*)&b1[h * 128 + w * 32 + tt * 16 + lg * 4];
#pragma unroll
          for (int mt = 0; mt < 2; ++mt) {
            f32x4 v = acc1[tt][mt] + b1v;
            v[0] = fmaxf(v[0], 0.f); v[1] = fmaxf(v[1], 0.f);
            v[2] = fmaxf(v[2], 0.f); v[3] = fmaxf(v[3], 0.f);
            int m = mt * 16 + l15;
            int n1l = w * 32 + tt * 16 + lg * 4;
            int byte = (m * 256 + n1l * 2) ^ ((m & 7) << 4);
            *(uint2*)(Hb + byte) = make_uint2(pk2(v[0], v[1]), pk2(v[2], v[3]));
          }
        }
      }
      if (s + 1 < 64) {
        char* nb = Wb + ((s + 1) & 1) * 8192;
        *(uint4*)(nb + t * 16) = rA0;
        *(uint4*)(nb + (t + 256) * 16) = rA1;
      }
      __syncthreads();
      rA0 = rB0; rA1 = rB1;
      ++s;
    }

    // ---- GEMM2 partial: n2 = h2*128 + w*32 + nf*16 + l15, k2-local = kk2*32 + lg*8 ----
#pragma unroll
    for (int h2 = 0; h2 < 2; ++h2) {
#pragma unroll
      for (int kk2 = 0; kk2 < 4; ++kk2) {
        if (s + 2 < 64) { const uint4* g = slab_ptr(s + 2); rB0 = g[t]; rB1 = g[t + 256]; }
        const char* buf = Wb + (s & 1) * 8192;
        bf16x8 hfr[2], wfr[2];
#pragma unroll
        for (int mt = 0; mt < 2; ++mt) {
          int m = mt * 16 + l15;
          int byte = (m * 256 + kk2 * 64 + lg * 16) ^ ((m & 7) << 4);
          hfr[mt] = *(const bf16x8*)(Hb + byte);
        }
#pragma unroll
        for (int nf = 0; nf < 2; ++nf)
          wfr[nf] = *(const bf16x8*)(buf + lg * 2048 + (w * 32 + nf * 16 + l15) * 16);
#pragma unroll
        for (int mt = 0; mt < 2; ++mt)
#pragma unroll
          for (int nf = 0; nf < 2; ++nf)
            acc2[mt][h2 * 2 + nf] =
                __builtin_amdgcn_mfma_f32_16x16x32_bf16(hfr[mt], wfr[nf], acc2[mt][h2 * 2 + nf], 0, 0, 0);
        if (s + 1 < 64) {
          char* nb = Wb + ((s + 1) & 1) * 8192;
          *(uint4*)(nb + t * 16) = rA0;
          *(uint4*)(nb + (t + 256) * 16) = rA1;
        }
        __syncthreads();
        rA0 = rB0; rA1 = rB1;
        ++s;
      }
    }
  }

  // ---- Outs = acc2 + b2 (f32 LDS); graph factors (post-GEMM: stats region now dead) ----
#pragma unroll
  for (int nf = 0; nf < 4; ++nf) {
    int col = (nf >> 1) * 128 + w * 32 + (nf & 1) * 16 + l15;
    float b2v = b2[col];
#pragma unroll
    for (int mt = 0; mt < 2; ++mt)
#pragma unroll
      for (int jr = 0; jr < 4; ++jr)
        Outs[(mt * 16 + lg * 4 + jr) * 256 + col] = acc2[mt][nf][jr] + b2v;
  }
  if (t < 32) {
    int r = row0 + t;
    int g = (r < M) ? gid[r] : 0;
    gid_s[t] = g;
    gfs[t] = gfactor[g];
  }
  __syncthreads();

  // ---- LayerNorm stats: 8 threads per row ----
  {
    int row = t >> 3, sub = t & 7;
    float ssum = 0.f, ss = 0.f;
#pragma unroll
    for (int i = 0; i < 8; ++i) {
      f32x4 v = *(const f32x4*)&Outs[row * 256 + sub * 32 + i * 4];
      ssum += v[0] + v[1] + v[2] + v[3];
      ss += v[0] * v[0] + v[1] * v[1] + v[2] * v[2] + v[3] * v[3];
    }
    ssum += __shfl_xor(ssum, 1); ss += __shfl_xor(ss, 1);
    ssum += __shfl_xor(ssum, 2); ss += __shfl_xor(ss, 2);
    ssum += __shfl_xor(ssum, 4); ss += __shfl_xor(ss, 4);
    if (sub == 0) {
      float mean = ssum * (1.f / 256.f);
      float var = ss * (1.f / 256.f) - mean * mean;
      fstat[row * 2] = mean;
      fstat[row * 2 + 1] = rsqrtf(var + LNEPS);
    }
  }
  __syncthreads();

  // ---- finalize: LN affine, graph_normal, residual, store (+segmented pool) ----
  {
    float g_t = ln_g[t], bb_t = ln_b[t];
    float psum = 0.f;
    int curg = -1;
#pragma unroll 4
    for (int p = 0; p < 32; ++p) {
      int gr = row0 + p;
      if (gr < M) {
        float v = Outs[p * 256 + t];
        v = (v - fstat[p * 2]) * fstat[p * 2 + 1] * g_t + bb_t;
        v *= gfs[p];
        v += residual[(size_t)gr * HDIM + t];
        out_rows[(size_t)gr * HDIM + t] = v;
        if (POOL) {
          int g = gid_s[p];
          if (g != curg) {
            if (curg >= 0) atomicAdd(&pool_out[(size_t)curg * HDIM + t], psum);
            psum = 0.f;
            curg = g;
          }
          psum += v;
        }
      }
    }
    if (POOL && curg >= 0) atomicAdd(&pool_out[(size_t)curg * HDIM + t], psum);
  }
}

// ---------------- pooled sums -> means ----------------
__global__ void pooldiv_kernel(float* out_graph, const float* __restrict__ recip_node) {
  int g = blockIdx.x, t = threadIdx.x;
  out_graph[(size_t)g * HDIM + t] *= recip_node[g];
}

extern "C" void kernel_launch(void* const* d_in, const int* in_sizes, int n_in,
                              void* d_out, int out_size, void* d_ws, size_t ws_size,
                              hipStream_t stream) {
  const float* node_hidden = (const float*)d_in[0];
  const float* edge_hidden = (const float*)d_in[1];
  const float* bond_angle = (const float*)d_in[2];
  const int* ab_src = (const int*)d_in[3];
  const int* ab_dst = (const int*)d_in[4];
  const int* ba_src = (const int*)d_in[5];
  const int* ba_dst = (const int*)d_in[6];
  const int* node_gid = (const int*)d_in[7];
  const int* bond_gid = (const int*)d_in[8];
  const float* rbf_w = (const float*)d_in[10];
  const float* rbf_b = (const float*)d_in[11];
  const float* ba_w1 = (const float*)d_in[12];
  const float* ba_b1 = (const float*)d_in[13];
  const float* ba_w2 = (const float*)d_in[14];
  const float* ba_b2 = (const float*)d_in[15];
  const float* ba_ln_g = (const float*)d_in[16];
  const float* ba_ln_b = (const float*)d_in[17];
  const float* ab_w1 = (const float*)d_in[18];
  const float* ab_b1 = (const float*)d_in[19];
  const float* ab_w2 = (const float*)d_in[20];
  const float* ab_b2 = (const float*)d_in[21];
  const float* ab_ln_g = (const float*)d_in[22];
  const float* ab_ln_b = (const float*)d_in[23];

  int N = in_sizes[0] / HDIM;
  int E = in_sizes[1] / HDIM;
  int A = in_sizes[2];
  int G = out_size / HDIM - N - E;

  float* out_node = (float*)d_out;
  float* out_edge = out_node + (size_t)N * HDIM;
  float* out_graph = out_edge + (size_t)E * HDIM;

  // ---- workspace layout ----
  char* ws = (char*)d_ws;
  int* cnt_node = (int*)ws;                    // G   (zeroed)
  int* cnt_bond = cnt_node + G;                // G   (zeroed)
  int* deg_e = cnt_bond + G;                   // E   (zeroed)
  int* cur_e = deg_e + E;                      // E   (zeroed)
  int* deg_n = cur_e + E;                      // N   (zeroed)
  int* cur_n = deg_n + N;                      // N   (zeroed)
  size_t zero_bytes = (size_t)(2 * G + 2 * E + 2 * N) * 4;
  float* fac_node = (float*)(cur_n + N);       // G
  float* fac_bond = fac_node + G;              // G
  float* recip_node = fac_bond + G;            // G
  int* off_e = (int*)(recip_node + G);         // E
  int* csr_e = off_e + E;                      // A
  int* off_n = csr_e + A;                      // N
  int* csr_n = off_n + N;                      // E
  int* bsum = csr_n + E;                       // 1024
  size_t off = ((size_t)((char*)(bsum + 1024) - ws) + 255) & ~(size_t)255;
  unsigned short* w1p_ba = (unsigned short*)(ws + off); off += (size_t)512 * 256 * 2;
  unsigned short* w2p_ba = (unsigned short*)(ws + off); off += (size_t)256 * 512 * 2;
  unsigned short* w1p_ab = (unsigned short*)(ws + off); off += (size_t)512 * 256 * 2;
  unsigned short* w2p_ab = (unsigned short*)(ws + off); off += (size_t)256 * 512 * 2;

  hipMemsetAsync(d_ws, 0, zero_bytes, stream);
  hipMemsetAsync(out_graph, 0, (size_t)G * HDIM * 4, stream);

  pack1_kernel<<<512, 256, 0, stream>>>(ba_w1, w1p_ba);
  pack2_kernel<<<512, 256, 0, stream>>>(ba_w2, w2p_ba);
  pack1_kernel<<<512, 256, 0, stream>>>(ab_w1, w1p_ab);
  pack2_kernel<<<512, 256, 0, stream>>>(ab_w2, w2p_ab);

  count_kernel<<<(E + 255) / 256, 256, 0, stream>>>(node_gid, bond_gid, cnt_node, cnt_bond, N, E);
  factor_kernel<<<(G + 255) / 256, 256, 0, stream>>>(cnt_node, cnt_bond, fac_node, fac_bond,
                                                     recip_node, G);

  // ---- CSR for bond-angle graph ----
  deg_kernel<<<(A + 255) / 256, 256, 0, stream>>>(ba_dst, deg_e, A);
  int nbE = (E + 255) / 256;
  scan1_kernel<<<nbE, 256, 0, stream>>>(deg_e, off_e, bsum, E);
  scan2_kernel<<<1, 1024, 0, stream>>>(bsum, nbE);
  scan3_kernel<<<nbE, 256, 0, stream>>>(off_e, bsum, E);
  fill_kernel<<<(A + 255) / 256, 256, 0, stream>>>(ba_dst, off_e, cur_e, csr_e, A);

  angle_gather_kernel<<<(E + 3) / 4, 256, 0, stream>>>(bond_angle, ba_src, edge_hidden,
                                                       off_e, deg_e, csr_e, rbf_w, rbf_b,
                                                       out_edge, E);
  mlp_kernel<0><<<(E + 31) / 32, 256, 0, stream>>>(out_edge, out_edge, edge_hidden, bond_gid,
                                                   fac_bond, w1p_ba, ba_b1, w2p_ba, ba_b2,
                                                   ba_ln_g, ba_ln_b, nullptr, E);

  // ---- CSR for atom-bond graph ----
  deg_kernel<<<(E + 255) / 256, 256, 0, stream>>>(ab_dst, deg_n, E);
  int nbN = (N + 255) / 256;
  scan1_kernel<<<nbN, 256, 0, stream>>>(deg_n, off_n, bsum, N);
  scan2_kernel<<<1, 1024, 0, stream>>>(bsum, nbN);
  scan3_kernel<<<nbN, 256, 0, stream>>>(off_n, bsum, N);
  fill_kernel<<<(E + 255) / 256, 256, 0, stream>>>(ab_dst, off_n, cur_n, csr_n, E);

  node_gather_kernel<<<(N + 3) / 4, 256, 0, stream>>>(node_hidden, out_edge, ab_src,
                                                      off_n, deg_n, csr_n, out_node, N);
  mlp_kernel<1><<<(N + 31) / 32, 256, 0, stream>>>(out_node, out_node, node_hidden, node_gid,
                                                   fac_node, w1p_ab, ab_b1, w2p_ab, ab_b2,
                                                   ab_ln_g, ab_ln_b, out_graph, N);

  pooldiv_kernel<<<G, 256, 0, stream>>>(out_graph, recip_node);
}

// Round 9
// 610.728 us; speedup vs baseline: 1.8635x; 1.0605x over previous
//
#include <hip/hip_runtime.h>

#define HDIM 256
#define LNEPS 1e-5f

typedef float f32x4 __attribute__((ext_vector_type(4)));
typedef short bf16x8 __attribute__((ext_vector_type(8)));

static __device__ __forceinline__ unsigned short f2b(float f) {
  union { float f; unsigned u; } v; v.f = f;
  return (unsigned short)((v.u + 0x7fffu + ((v.u >> 16) & 1u)) >> 16);
}
static __device__ __forceinline__ unsigned pk2(float lo, float hi) {
  return (unsigned)f2b(lo) | ((unsigned)f2b(hi) << 16);
}

// ---------------- weight repack into 8KB fragment-ordered slabs ----------------
// Transposed [lg][n1l] layout: fragment byte = lg*2048 + n1l*16 (conflict-free ds_read).
__global__ void pack1_kernel(const float* __restrict__ in, unsigned short* __restrict__ out) {
  int o = blockIdx.x * 256 + threadIdx.x;  // 131072
  int ke = o & 7, n1l = (o >> 3) & 127, lg = (o >> 10) & 3, sl = o >> 12;
  int h = sl >> 3, kk = sl & 7;
  int k = kk * 32 + lg * 8 + ke, n1 = h * 128 + n1l;
  out[o] = f2b(in[k * 512 + n1]);
}

__global__ void pack2_kernel(const float* __restrict__ in, unsigned short* __restrict__ out) {
  int o = blockIdx.x * 256 + threadIdx.x;  // 131072
  int ke = o & 7, n2l = (o >> 3) & 127, lg = (o >> 10) & 3, sl = o >> 12;
  int h = sl >> 3, r = sl & 7, h2 = r >> 2, kk2 = r & 3;
  int k2 = h * 128 + kk2 * 32 + lg * 8 + ke, n2 = h2 * 128 + n2l;
  out[o] = f2b(in[k2 * 256 + n2]);
}

// ---------------- per-graph counts ----------------
__global__ void count_kernel(const int* __restrict__ node_gid, const int* __restrict__ bond_gid,
                             int* cnt_node, int* cnt_bond, int N, int E) {
  int i = blockIdx.x * 256 + threadIdx.x;
  if (i < N) atomicAdd(&cnt_node[node_gid[i]], 1);
  if (i < E) atomicAdd(&cnt_bond[bond_gid[i]], 1);
}

__global__ void factor_kernel(const int* __restrict__ cnt_node, const int* __restrict__ cnt_bond,
                              float* fac_node, float* fac_bond, float* recip_node, int G) {
  int g = blockIdx.x * 256 + threadIdx.x;
  if (g >= G) return;
  float cn = fmaxf((float)cnt_node[g], 1.f);
  float cb = fmaxf((float)cnt_bond[g], 1.f);
  fac_node[g] = rsqrtf(cn);
  fac_bond[g] = rsqrtf(cb);
  recip_node[g] = 1.f / cn;
}

// ---------------- CSR build ----------------
__global__ void deg_kernel(const int* __restrict__ dst, int* __restrict__ deg, int n) {
  int i = blockIdx.x * 256 + threadIdx.x;
  if (i < n) atomicAdd(&deg[dst[i]], 1);
}

__global__ void scan1_kernel(const int* __restrict__ deg, int* __restrict__ excl,
                             int* __restrict__ bsum, int n) {
  int t = threadIdx.x;
  int i = blockIdx.x * 256 + t;
  int v = (i < n) ? deg[i] : 0;
  int lane = t & 63, w = t >> 6;
  int s = v;
#pragma unroll
  for (int d = 1; d < 64; d <<= 1) {
    int u = __shfl_up(s, d);
    if (lane >= d) s += u;
  }
  __shared__ int wsum[4];
  if (lane == 63) wsum[w] = s;
  __syncthreads();
  int base = 0;
  for (int ww = 0; ww < w; ++ww) base += wsum[ww];
  if (i < n) excl[i] = base + s - v;
  if (t == 255) bsum[blockIdx.x] = base + s;
}

__global__ void scan2_kernel(int* __restrict__ bsum, int nb) {
  int t = threadIdx.x;  // 1024 threads
  int v = (t < nb) ? bsum[t] : 0;
  int lane = t & 63, w = t >> 6;
  int s = v;
#pragma unroll
  for (int d = 1; d < 64; d <<= 1) {
    int u = __shfl_up(s, d);
    if (lane >= d) s += u;
  }
  __shared__ int wsum[16];
  if (lane == 63) wsum[w] = s;
  __syncthreads();
  int base = 0;
  for (int ww = 0; ww < w; ++ww) base += wsum[ww];
  if (t < nb) bsum[t] = base + s - v;
}

__global__ void scan3_kernel(int* __restrict__ excl, const int* __restrict__ bsum, int n) {
  int i = blockIdx.x * 256 + threadIdx.x;
  if (i < n) excl[i] += bsum[blockIdx.x];
}

__global__ void fill_kernel(const int* __restrict__ dst, const int* __restrict__ off,
                            int* __restrict__ cursor, int* __restrict__ csr, int n) {
  int i = blockIdx.x * 256 + threadIdx.x;
  if (i >= n) return;
  int d = dst[i];
  int p = atomicAdd(&cursor[d], 1);
  csr[off[d] + p] = i;
}

// ---------------- gather: agg_e[d] = (Σ rbf_a)@W + cnt·b + Σ edge_hidden[src_a] ----------
// LDS-STAGED rbf_w (fix for round-8's L1-port wall): the 32-iter R@W loop read the
// whole 32KB rbf_w table from L1 PER WAVE (32 of ~36 1KB L1 transactions/wave, ~16cyc
// each = ~57% of the wall). Now staged to LDS once per block and amortized over 8 rows
// (2 rows/wave); projection reads hit LDS (128B/cyc, consecutive-16B = conflict-free).
__global__ __launch_bounds__(256) void angle_gather_kernel(
    const float* __restrict__ bond_angle, const int* __restrict__ ba_src,
    const float* __restrict__ edge_hidden,
    const int* __restrict__ off, const int* __restrict__ deg, const int* __restrict__ csr,
    const float* __restrict__ rbf_w, const float* __restrict__ rbf_b,
    float* __restrict__ agg_e, int E) {
  __shared__ float rbfw_s[32 * 256];  // 32KB
  int t = threadIdx.x;
  int w = t >> 6, lane = t & 63;
#pragma unroll
  for (int i = 0; i < 8; ++i)
    *(f32x4*)&rbfw_s[(t + i * 256) * 4] = *(const f32x4*)&rbf_w[(t + i * 256) * 4];
  __syncthreads();
  int c4 = lane * 4;
  f32x4 bv = *(const f32x4*)&rbf_b[c4];
  float cc = 0.1f * (float)(lane & 31);
  for (int rr = 0; rr < 2; ++rr) {
    int d = blockIdx.x * 8 + w * 2 + rr;
    if (d >= E) break;
    int start = off[d], cnt = deg[d];
    f32x4 acc = (f32x4)0.f;
    float rbfs = 0.f;
    for (int base = 0; base < cnt; base += 64) {
      int n = cnt - base; if (n > 64) n = 64;
      float av = 0.f;
      int s = 0;
      if (lane < n) {
        int a = csr[start + base + lane];
        av = bond_angle[a];
        s = ba_src[a];
      }
#pragma unroll 4
      for (int i = 0; i < n; ++i) {
        float avi = __shfl(av, i);
        int si = __shfl(s, i);
        if (lane < 32) {
          float dd = avi - cc;
          rbfs += __expf(-10.f * dd * dd);
        }
        acc += *(const f32x4*)&edge_hidden[(size_t)si * HDIM + c4];
      }
    }
#pragma unroll 8
    for (int k = 0; k < 32; ++k) {
      float rv = __shfl(rbfs, k);
      f32x4 wv = *(const f32x4*)&rbfw_s[k * 256 + c4];
      acc[0] += rv * wv[0]; acc[1] += rv * wv[1];
      acc[2] += rv * wv[2]; acc[3] += rv * wv[3];
    }
    float fc = (float)cnt;
    acc[0] += fc * bv[0]; acc[1] += fc * bv[1];
    acc[2] += fc * bv[2]; acc[3] += fc * bv[3];
    *(f32x4*)&agg_e[(size_t)d * HDIM + c4] = acc;
  }
}

// ---------------- gather: agg_n[d] = Σ (edge_out[e] + node_hidden[src_e]) --------------
// Lane-parallel index chase (R8); per-wave L1 traffic is already lean (~5 1KB loads).
__global__ __launch_bounds__(256) void node_gather_kernel(
    const float* __restrict__ node_hidden, const float* __restrict__ edge_out,
    const int* __restrict__ ab_src,
    const int* __restrict__ off, const int* __restrict__ deg, const int* __restrict__ csr,
    float* __restrict__ agg_n, int N) {
  int w = threadIdx.x >> 6, lane = threadIdx.x & 63;
  int d = blockIdx.x * 4 + w;
  if (d >= N) return;
  int c4 = lane * 4;
  int start = off[d], cnt = deg[d];
  f32x4 acc = (f32x4)0.f;
  for (int base = 0; base < cnt; base += 64) {
    int n = cnt - base; if (n > 64) n = 64;
    int e = 0, s = 0;
    if (lane < n) {
      e = csr[start + base + lane];
      s = ab_src[e];
    }
#pragma unroll 4
    for (int i = 0; i < n; ++i) {
      int ei = __shfl(e, i);
      int si = __shfl(s, i);
      f32x4 a = *(const f32x4*)&edge_out[(size_t)ei * HDIM + c4];
      f32x4 b = *(const f32x4*)&node_hidden[(size_t)si * HDIM + c4];
      acc += a;
      acc += b;
    }
  }
  *(f32x4*)&agg_n[(size_t)d * HDIM + c4] = acc;
}

// ---------------- fused MLP + LayerNorm + graph_normal + residual (+pool) ----------------
// (frozen from round 7: 64 slab-steps, distance-2 prefetch, transposed slabs)
template <int POOL>
__global__ __launch_bounds__(256, 4) void mlp_kernel(
    const float* agg_in, float* out_rows,  // may alias (in-place per-block)
    const float* __restrict__ residual, const int* __restrict__ gid,
    const float* __restrict__ gfactor,
    const unsigned short* __restrict__ w1p, const float* __restrict__ b1,
    const unsigned short* __restrict__ w2p, const float* __restrict__ b2,
    const float* __restrict__ ln_g, const float* __restrict__ ln_b,
    float* pool_out, int M) {
  __shared__ __align__(16) char smem[40960];
  char* Xb = smem;                         // bf16 [32][256] swizzled, 16KB
  char* Hb = smem + 16384;                 // bf16 [32][128] quarter, swizzled, 8KB
  char* Wb = smem + 24576;                 // 2 x 8KB weight-slab double buffer
  float* Outs = (float*)smem;              // f32 [32][256], overlays Xb+Hb+Wb[0] post-GEMM
  float* fstat = (float*)(smem + 40448);   // [32][2] mean/rstd (in dead Wb[1] tail)
  float* gfs = (float*)(smem + 40704);     // [32]
  int* gid_s = (int*)(smem + 40832);       // [32]

  int t = threadIdx.x;
  int row0 = blockIdx.x * 32;
  int w = t >> 6, lane = t & 63;
  int l15 = lane & 15, lg = lane >> 4;

  auto slab_ptr = [&](int ss) -> const uint4* {
    int hh = ss >> 4, r = ss & 15;
    const unsigned short* p = (r < 8) ? (w1p + (size_t)(hh * 8 + r) * 4096)
                                      : (w2p + (size_t)(hh * 8 + (r - 8)) * 4096);
    return (const uint4*)p;
  };

  uint4 rA0, rA1, rB0, rB1;  // in-flight slab registers (named, never runtime-indexed)

  // ---- prologue: slab0 -> Wb[0]; slab1 -> regs; stage X (f32 -> bf16 swizzled) ----
  {
    const uint4* g0 = slab_ptr(0);
    uint4 s0a = g0[t], s0b = g0[t + 256];
    const uint4* g1 = slab_ptr(1);
    rA0 = g1[t]; rA1 = g1[t + 256];
    int row = t >> 3;
    int c0 = (t & 7) * 32;
    int gr = row0 + row; if (gr >= M) gr = M - 1;
    const float* src = agg_in + (size_t)gr * HDIM + c0;
#pragma unroll
    for (int i = 0; i < 4; ++i) {
      f32x4 a = *(const f32x4*)(src + i * 8);
      f32x4 b = *(const f32x4*)(src + i * 8 + 4);
      int byte = (row * 512 + (c0 + i * 8) * 2) ^ ((row & 7) << 4);
      *(uint4*)(Xb + byte) =
          make_uint4(pk2(a[0], a[1]), pk2(a[2], a[3]), pk2(b[0], b[1]), pk2(b[2], b[3]));
    }
    *(uint4*)(Wb + t * 16) = s0a;
    *(uint4*)(Wb + (t + 256) * 16) = s0b;
  }
  __syncthreads();

  f32x4 acc2[2][4];  // [mt][h2*2+nf] : row = mt*16+lg*4+jr ; col = h2*128+w*32+nf*16+l15
#pragma unroll
  for (int mt = 0; mt < 2; ++mt)
#pragma unroll
    for (int nf = 0; nf < 4; ++nf) acc2[mt][nf] = (f32x4)0.f;

  int s = 0;
  for (int h = 0; h < 4; ++h) {
    f32x4 acc1[2][2];  // [tt][mt]
#pragma unroll
    for (int tt = 0; tt < 2; ++tt)
#pragma unroll
      for (int mt = 0; mt < 2; ++mt) acc1[tt][mt] = (f32x4)0.f;

    // ---- GEMM1 quarter: n1 = h*128 + w*32 + tt*16 + l15, k = kk*32 + lg*8 ----
    for (int kk = 0; kk < 8; ++kk) {
      if (s + 2 < 64) { const uint4* g = slab_ptr(s + 2); rB0 = g[t]; rB1 = g[t + 256]; }
      const char* buf = Wb + (s & 1) * 8192;
      bf16x8 xfr[2], afr[2];
#pragma unroll
      for (int mt = 0; mt < 2; ++mt) {
        int m = mt * 16 + l15;
        int byte = (m * 512 + kk * 64 + lg * 16) ^ ((m & 7) << 4);
        xfr[mt] = *(const bf16x8*)(Xb + byte);
      }
#pragma unroll
      for (int tt = 0; tt < 2; ++tt)
        afr[tt] = *(const bf16x8*)(buf + lg * 2048 + (w * 32 + tt * 16 + l15) * 16);
#pragma unroll
      for (int tt = 0; tt < 2; ++tt)
#pragma unroll
        for (int mt = 0; mt < 2; ++mt)
          acc1[tt][mt] = __builtin_amdgcn_mfma_f32_16x16x32_bf16(afr[tt], xfr[mt], acc1[tt][mt], 0, 0, 0);

      if (kk == 7) {
        // bias + relu + packed Hb store: Hb[m][n1l], n1l = w*32 + tt*16 + lg*4 (+0..3)
#pragma unroll
        for (int tt = 0; tt < 2; ++tt) {
          f32x4 b1v = *(const f32x4*)&b1[h * 128 + w * 32 + tt * 16 + lg * 4];
#pragma unroll
          for (int mt = 0; mt < 2; ++mt) {
            f32x4 v = acc1[tt][mt] + b1v;
            v[0] = fmaxf(v[0], 0.f); v[1] = fmaxf(v[1], 0.f);
            v[2] = fmaxf(v[2], 0.f); v[3] = fmaxf(v[3], 0.f);
            int m = mt * 16 + l15;
            int n1l = w * 32 + tt * 16 + lg * 4;
            int byte = (m * 256 + n1l * 2) ^ ((m & 7) << 4);
            *(uint2*)(Hb + byte) = make_uint2(pk2(v[0], v[1]), pk2(v[2], v[3]));
          }
        }
      }
      if (s + 1 < 64) {
        char* nb = Wb + ((s + 1) & 1) * 8192;
        *(uint4*)(nb + t * 16) = rA0;
        *(uint4*)(nb + (t + 256) * 16) = rA1;
      }
      __syncthreads();
      rA0 = rB0; rA1 = rB1;
      ++s;
    }

    // ---- GEMM2 partial: n2 = h2*128 + w*32 + nf*16 + l15, k2-local = kk2*32 + lg*8 ----
#pragma unroll
    for (int h2 = 0; h2 < 2; ++h2) {
#pragma unroll
      for (int kk2 = 0; kk2 < 4; ++kk2) {
        if (s + 2 < 64) { const uint4* g = slab_ptr(s + 2); rB0 = g[t]; rB1 = g[t + 256]; }
        const char* buf = Wb + (s & 1) * 8192;
        bf16x8 hfr[2], wfr[2];
#pragma unroll
        for (int mt = 0; mt < 2; ++mt) {
          int m = mt * 16 + l15;
          int byte = (m * 256 + kk2 * 64 + lg * 16) ^ ((m & 7) << 4);
          hfr[mt] = *(const bf16x8*)(Hb + byte);
        }
#pragma unroll
        for (int nf = 0; nf < 2; ++nf)
          wfr[nf] = *(const bf16x8*)(buf + lg * 2048 + (w * 32 + nf * 16 + l15) * 16);
#pragma unroll
        for (int mt = 0; mt < 2; ++mt)
#pragma unroll
          for (int nf = 0; nf < 2; ++nf)
            acc2[mt][h2 * 2 + nf] =
                __builtin_amdgcn_mfma_f32_16x16x32_bf16(hfr[mt], wfr[nf], acc2[mt][h2 * 2 + nf], 0, 0, 0);
        if (s + 1 < 64) {
          char* nb = Wb + ((s + 1) & 1) * 8192;
          *(uint4*)(nb + t * 16) = rA0;
          *(uint4*)(nb + (t + 256) * 16) = rA1;
        }
        __syncthreads();
        rA0 = rB0; rA1 = rB1;
        ++s;
      }
    }
  }

  // ---- Outs = acc2 + b2 (f32 LDS); graph factors (post-GEMM: stats region now dead) ----
#pragma unroll
  for (int nf = 0; nf < 4; ++nf) {
    int col = (nf >> 1) * 128 + w * 32 + (nf & 1) * 16 + l15;
    float b2v = b2[col];
#pragma unroll
    for (int mt = 0; mt < 2; ++mt)
#pragma unroll
      for (int jr = 0; jr < 4; ++jr)
        Outs[(mt * 16 + lg * 4 + jr) * 256 + col] = acc2[mt][nf][jr] + b2v;
  }
  if (t < 32) {
    int r = row0 + t;
    int g = (r < M) ? gid[r] : 0;
    gid_s[t] = g;
    gfs[t] = gfactor[g];
  }
  __syncthreads();

  // ---- LayerNorm stats: 8 threads per row ----
  {
    int row = t >> 3, sub = t & 7;
    float ssum = 0.f, ss = 0.f;
#pragma unroll
    for (int i = 0; i < 8; ++i) {
      f32x4 v = *(const f32x4*)&Outs[row * 256 + sub * 32 + i * 4];
      ssum += v[0] + v[1] + v[2] + v[3];
      ss += v[0] * v[0] + v[1] * v[1] + v[2] * v[2] + v[3] * v[3];
    }
    ssum += __shfl_xor(ssum, 1); ss += __shfl_xor(ss, 1);
    ssum += __shfl_xor(ssum, 2); ss += __shfl_xor(ss, 2);
    ssum += __shfl_xor(ssum, 4); ss += __shfl_xor(ss, 4);
    if (sub == 0) {
      float mean = ssum * (1.f / 256.f);
      float var = ss * (1.f / 256.f) - mean * mean;
      fstat[row * 2] = mean;
      fstat[row * 2 + 1] = rsqrtf(var + LNEPS);
    }
  }
  __syncthreads();

  // ---- finalize: LN affine, graph_normal, residual, store (+segmented pool) ----
  {
    float g_t = ln_g[t], bb_t = ln_b[t];
    float psum = 0.f;
    int curg = -1;
#pragma unroll 4
    for (int p = 0; p < 32; ++p) {
      int gr = row0 + p;
      if (gr < M) {
        float v = Outs[p * 256 + t];
        v = (v - fstat[p * 2]) * fstat[p * 2 + 1] * g_t + bb_t;
        v *= gfs[p];
        v += residual[(size_t)gr * HDIM + t];
        out_rows[(size_t)gr * HDIM + t] = v;
        if (POOL) {
          int g = gid_s[p];
          if (g != curg) {
            if (curg >= 0) atomicAdd(&pool_out[(size_t)curg * HDIM + t], psum);
            psum = 0.f;
            curg = g;
          }
          psum += v;
        }
      }
    }
    if (POOL && curg >= 0) atomicAdd(&pool_out[(size_t)curg * HDIM + t], psum);
  }
}

// ---------------- pooled sums -> means ----------------
__global__ void pooldiv_kernel(float* out_graph, const float* __restrict__ recip_node) {
  int g = blockIdx.x, t = threadIdx.x;
  out_graph[(size_t)g * HDIM + t] *= recip_node[g];
}

extern "C" void kernel_launch(void* const* d_in, const int* in_sizes, int n_in,
                              void* d_out, int out_size, void* d_ws, size_t ws_size,
                              hipStream_t stream) {
  const float* node_hidden = (const float*)d_in[0];
  const float* edge_hidden = (const float*)d_in[1];
  const float* bond_angle = (const float*)d_in[2];
  const int* ab_src = (const int*)d_in[3];
  const int* ab_dst = (const int*)d_in[4];
  const int* ba_src = (const int*)d_in[5];
  const int* ba_dst = (const int*)d_in[6];
  const int* node_gid = (const int*)d_in[7];
  const int* bond_gid = (const int*)d_in[8];
  const float* rbf_w = (const float*)d_in[10];
  const float* rbf_b = (const float*)d_in[11];
  const float* ba_w1 = (const float*)d_in[12];
  const float* ba_b1 = (const float*)d_in[13];
  const float* ba_w2 = (const float*)d_in[14];
  const float* ba_b2 = (const float*)d_in[15];
  const float* ba_ln_g = (const float*)d_in[16];
  const float* ba_ln_b = (const float*)d_in[17];
  const float* ab_w1 = (const float*)d_in[18];
  const float* ab_b1 = (const float*)d_in[19];
  const float* ab_w2 = (const float*)d_in[20];
  const float* ab_b2 = (const float*)d_in[21];
  const float* ab_ln_g = (const float*)d_in[22];
  const float* ab_ln_b = (const float*)d_in[23];

  int N = in_sizes[0] / HDIM;
  int E = in_sizes[1] / HDIM;
  int A = in_sizes[2];
  int G = out_size / HDIM - N - E;

  float* out_node = (float*)d_out;
  float* out_edge = out_node + (size_t)N * HDIM;
  float* out_graph = out_edge + (size_t)E * HDIM;

  // ---- workspace layout ----
  char* ws = (char*)d_ws;
  int* cnt_node = (int*)ws;                    // G   (zeroed)
  int* cnt_bond = cnt_node + G;                // G   (zeroed)
  int* deg_e = cnt_bond + G;                   // E   (zeroed)
  int* cur_e = deg_e + E;                      // E   (zeroed)
  int* deg_n = cur_e + E;                      // N   (zeroed)
  int* cur_n = deg_n + N;                      // N   (zeroed)
  size_t zero_bytes = (size_t)(2 * G + 2 * E + 2 * N) * 4;
  float* fac_node = (float*)(cur_n + N);       // G
  float* fac_bond = fac_node + G;              // G
  float* recip_node = fac_bond + G;            // G
  int* off_e = (int*)(recip_node + G);         // E
  int* csr_e = off_e + E;                      // A
  int* off_n = csr_e + A;                      // N
  int* csr_n = off_n + N;                      // E
  int* bsum = csr_n + E;                       // 1024
  size_t off = ((size_t)((char*)(bsum + 1024) - ws) + 255) & ~(size_t)255;
  unsigned short* w1p_ba = (unsigned short*)(ws + off); off += (size_t)512 * 256 * 2;
  unsigned short* w2p_ba = (unsigned short*)(ws + off); off += (size_t)256 * 512 * 2;
  unsigned short* w1p_ab = (unsigned short*)(ws + off); off += (size_t)512 * 256 * 2;
  unsigned short* w2p_ab = (unsigned short*)(ws + off); off += (size_t)256 * 512 * 2;

  hipMemsetAsync(d_ws, 0, zero_bytes, stream);
  hipMemsetAsync(out_graph, 0, (size_t)G * HDIM * 4, stream);

  pack1_kernel<<<512, 256, 0, stream>>>(ba_w1, w1p_ba);
  pack2_kernel<<<512, 256, 0, stream>>>(ba_w2, w2p_ba);
  pack1_kernel<<<512, 256, 0, stream>>>(ab_w1, w1p_ab);
  pack2_kernel<<<512, 256, 0, stream>>>(ab_w2, w2p_ab);

  count_kernel<<<(E + 255) / 256, 256, 0, stream>>>(node_gid, bond_gid, cnt_node, cnt_bond, N, E);
  factor_kernel<<<(G + 255) / 256, 256, 0, stream>>>(cnt_node, cnt_bond, fac_node, fac_bond,
                                                     recip_node, G);

  // ---- CSR for bond-angle graph ----
  deg_kernel<<<(A + 255) / 256, 256, 0, stream>>>(ba_dst, deg_e, A);
  int nbE = (E + 255) / 256;
  scan1_kernel<<<nbE, 256, 0, stream>>>(deg_e, off_e, bsum, E);
  scan2_kernel<<<1, 1024, 0, stream>>>(bsum, nbE);
  scan3_kernel<<<nbE, 256, 0, stream>>>(off_e, bsum, E);
  fill_kernel<<<(A + 255) / 256, 256, 0, stream>>>(ba_dst, off_e, cur_e, csr_e, A);

  angle_gather_kernel<<<(E + 7) / 8, 256, 0, stream>>>(bond_angle, ba_src, edge_hidden,
                                                       off_e, deg_e, csr_e, rbf_w, rbf_b,
                                                       out_edge, E);
  mlp_kernel<0><<<(E + 31) / 32, 256, 0, stream>>>(out_edge, out_edge, edge_hidden, bond_gid,
                                                   fac_bond, w1p_ba, ba_b1, w2p_ba, ba_b2,
                                                   ba_ln_g, ba_ln_b, nullptr, E);

  // ---- CSR for atom-bond graph ----
  deg_kernel<<<(E + 255) / 256, 256, 0, stream>>>(ab_dst, deg_n, E);
  int nbN = (N + 255) / 256;
  scan1_kernel<<<nbN, 256, 0, stream>>>(deg_n, off_n, bsum, N);
  scan2_kernel<<<1, 1024, 0, stream>>>(bsum, nbN);
  scan3_kernel<<<nbN, 256, 0, stream>>>(off_n, bsum, N);
  fill_kernel<<<(E + 255) / 256, 256, 0, stream>>>(ab_dst, off_n, cur_n, csr_n, E);

  node_gather_kernel<<<(N + 3) / 4, 256, 0, stream>>>(node_hidden, out_edge, ab_src,
                                                      off_n, deg_n, csr_n, out_node, N);
  mlp_kernel<1><<<(N + 31) / 32, 256, 0, stream>>>(out_node, out_node, node_hidden, node_gid,
                                                   fac_node, w1p_ab, ab_b1, w2p_ab, ab_b2,
                                                   ab_ln_g, ab_ln_b, out_graph, N);

  pooldiv_kernel<<<G, 256, 0, stream>>>(out_graph, recip_node);
}